// Round 6
// baseline (535.068 us; speedup 1.0000x reference)
//
#include <hip/hip_runtime.h>
#include <hip/hip_fp16.h>
#include <math.h>

// GNN power-flow forward. N=100k, E=3.2M, H=32, L=3, FE=4.
// R16: L0 gather restructure + streaming L1/2 gather.
//  R15 evidence: L0 gather 68us at 31.9% occupancy (82KB LDS -> 1 blk/CU),
//  1.75M LDS bank conflicts in the grouping phase; z16 traffic is near its
//  8-XCD compulsory floor (~51MB/layer), so cut overheads instead:
//  - L0: ef-sums accumulated in fp32 LDS afAcc DURING the phase-A scatter
//    (4 LDS float atomics/record) -> no 40KB bG staging -> 34KB LDS ->
//    2 blocks/CU.
//  - L0 writes the grouped order back as gs(4B)+gm(2B fp16) ALIASED into the
//    bA region it just consumed (per-partition; reads drained before writes
//    by __syncthreads vmcnt semantics) + packed start|len per receiver.
//  - L1/2 = gather_lite: 256-thr blocks, stream 6B/record grouped senders
//    (no hist/scan/scatter, no LDS staging), gather z16, F16 epilogue.
// pass1, init_z, update unchanged.

#define HH 32        // hidden dim
#define BSH 7        // bucket shift: 128 receivers per partition
#define MAXB 1024    // max partitions (N <= 131072)
#define P2CAP 4992   // fixed per-partition record capacity (path 2)
#define P1_TPB 1024  // pass1 threads per block
#define P1_EPT 8     // pass1 edges per thread
#define P1_EPB (P1_TPB * P1_EPT)   // 8192 edges per block

typedef float rawf4 __attribute__((ext_vector_type(4)));

__device__ __forceinline__ unsigned pack2h(float a, float b) {
    return ((unsigned)__half_as_ushort(__float2half_rn(b)) << 16) |
           (unsigned)__half_as_ushort(__float2half_rn(a));
}
__device__ __forceinline__ __half2 uash2(unsigned u) {
    return *reinterpret_cast<__half2*>(&u);
}
__device__ __forceinline__ unsigned h2asu(__half2 h) {
    return *reinterpret_cast<unsigned*>(&h);
}

// ---------------- build (path 2) ----------------

// pass 1: block-local LDS binning. 8192 edges/block -> LDS hist over
// partitions -> LDS scan -> one global reservation per partition ->
// scatter records into LDS -> coalesced SoA copy-out (A + B arrays).
__global__ void __launch_bounds__(P1_TPB)
pass1_bin_kernel(const int* __restrict__ snd, const int* __restrict__ rcv,
                 const float* __restrict__ mask, const float* __restrict__ ef,
                 int* __restrict__ tail,
                 uint2* __restrict__ bA, uint2* __restrict__ bB,
                 int E, int nbuck, int bcap)
{
    __shared__ float4 srec[P1_EPB];            // 128KB
    __shared__ unsigned short sbid[P1_EPB];    // 16KB
    __shared__ int cur[MAXB];
    __shared__ int dlt[MAXB];
    int lo = blockIdx.x * P1_EPB;
    int n = E - lo; if (n > P1_EPB) n = P1_EPB;
    int t = threadIdx.x;

    for (int i = t; i < MAXB; i += P1_TPB) cur[i] = 0;
    __syncthreads();

    int rv[P1_EPT];
#pragma unroll
    for (int i = 0; i < P1_EPT; i++) {
        int e = lo + t + i * P1_TPB;
        int r = (e < E) ? rcv[e] : -1;
        rv[i] = r;
        if (r >= 0) atomicAdd(&cur[r >> BSH], 1);
    }
    __syncthreads();

    int v = (t < nbuck) ? cur[t] : 0;
    dlt[t] = v;
    __syncthreads();
    for (int off = 1; off < P1_TPB; off <<= 1) {
        int x = (t >= off) ? dlt[t - off] : 0;
        __syncthreads();
        dlt[t] += x;
        __syncthreads();
    }
    int lstart = dlt[t] - v;
    int gbase = 0;
    if (t < nbuck && v > 0) gbase = atomicAdd(&tail[t], v);
    __syncthreads();
    cur[t] = lstart;
    dlt[t] = gbase - lstart;
    __syncthreads();

#pragma unroll
    for (int i = 0; i < P1_EPT; i++) {
        int r = rv[i];
        if (r < 0) continue;
        int e = lo + t + i * P1_TPB;
        int b = r >> BSH;
        int pos = atomicAdd(&cur[b], 1);
        int s = snd[e];
        float mk = mask[e];
        float4 f = *(const float4*)(ef + 4 * (size_t)e);
        float4 rec;
        rec.x = __int_as_float(s | ((r & ((1 << BSH) - 1)) << 20));
        rec.y = mk;
        rec.z = __uint_as_float(pack2h(mk * f.x, mk * f.y));
        rec.w = __uint_as_float(pack2h(mk * f.z, mk * f.w));
        srec[pos] = rec;
        sbid[pos] = (unsigned short)b;
    }
    __syncthreads();

    for (int i = t; i < n; i += P1_TPB) {
        int b = sbid[i];
        unsigned oin = (unsigned)(i + dlt[b]);
        if (oin < (unsigned)bcap) {
            float4 rec = srec[i];
            size_t o = (size_t)b * bcap + oin;
            uint2 a; a.x = __float_as_uint(rec.x); a.y = __float_as_uint(rec.y);
            bA[o] = a;
            uint2 bb; bb.x = __float_as_uint(rec.z); bb.y = __float_as_uint(rec.w);
            bB[o] = bb;
        }
    }
}

// L0 gather: one block per 128-receiver partition.
// Phase A: hist -> scan -> scatter {sender, mask_h} into grouped LDS lists,
//   accumulating fp32 afAcc (ef sums) per receiver along the way.
// Copy-out: grouped gs/gm written back into the (now-dead) bA region +
//   packed start|len per receiver, for the streaming L1/2 gathers.
// Phase B: per-receiver 8-lane z16 gather from LDS; epilogue writes F16.
__global__ void __launch_bounds__(1024)
gather0_kernel(const unsigned short* __restrict__ z16,
               const int* __restrict__ tail,
               uint2* bA,                     // NOT restrict: aliased re-write
               const uint2* __restrict__ bB,
               const float* __restrict__ We,  // [4,32] layer 0
               float* __restrict__ h,
               uint2* __restrict__ F16,
               unsigned* __restrict__ rl,
               float* __restrict__ pooled,
               int N)
{
    __shared__ unsigned aS[P2CAP];
    __shared__ unsigned short aM[P2CAP];
    __shared__ float afAcc[1 << BSH][4];
    __shared__ int hist[1 << BSH];
    __shared__ int bse[1 << BSH];
    __shared__ int cur[1 << BSH];
    __shared__ float sWe[4 * HH];
    __shared__ float sp[HH];
    int t = threadIdx.x, b = blockIdx.x;
    if (t < (1 << BSH)) {
        hist[t] = 0;
        afAcc[t][0] = 0.f; afAcc[t][1] = 0.f; afAcc[t][2] = 0.f; afAcc[t][3] = 0.f;
    }
    if (t < 4 * HH) sWe[t] = We[t];
    if (t < HH) sp[t] = 0.0f;
    __syncthreads();
    int n = tail[b];
    if (n > P2CAP) n = P2CAP;
    if (n < 0) n = 0;
    size_t gb = (size_t)b * P2CAP;

    // A1: histogram by rloc
    const unsigned* loA = (const unsigned*)(bA + gb);
    for (int i = t; i < n; i += 1024)
        atomicAdd(&hist[(loA[2 * i] >> 20) & ((1 << BSH) - 1)], 1);
    __syncthreads();

    // A2: exclusive scan over 128 rlocs
    if (t < (1 << BSH)) bse[t] = hist[t];
    __syncthreads();
    for (int off = 1; off < (1 << BSH); off <<= 1) {
        int x = (t < (1 << BSH) && t >= off) ? bse[t - off] : 0;
        __syncthreads();
        if (t < (1 << BSH)) bse[t] += x;
        __syncthreads();
    }
    if (t < (1 << BSH)) { int s0 = bse[t] - hist[t]; bse[t] = s0; cur[t] = s0; }
    __syncthreads();

    // A3: scatter grouped + fp32 af accumulation
    for (int i = t; i < n; i += 1024) {
        uint2 a = bA[gb + i];
        uint2 bb = bB[gb + i];
        int rloc = (a.x >> 20) & ((1 << BSH) - 1);
        int p = atomicAdd(&cur[rloc], 1);
        aS[p] = a.x & 0xFFFFF;
        aM[p] = __half_as_ushort(__float2half_rn(__uint_as_float(a.y)));
        float2 f01 = __half22float2(uash2(bb.x));
        float2 f23 = __half22float2(uash2(bb.y));
        atomicAdd(&afAcc[rloc][0], f01.x);
        atomicAdd(&afAcc[rloc][1], f01.y);
        atomicAdd(&afAcc[rloc][2], f23.x);
        atomicAdd(&afAcc[rloc][3], f23.y);
    }
    __syncthreads();   // all bA reads drained (vmcnt(0) before barrier)

    // copy-out grouped order into the dead bA region (per-partition alias)
    unsigned* gsb = (unsigned*)(bA + gb);
    unsigned short* gmb = (unsigned short*)((char*)(bA + gb) + 4 * P2CAP);
    for (int i = t; i < n; i += 1024) { gsb[i] = aS[i]; gmb[i] = aM[i]; }
    if (t < (1 << BSH)) {
        int rr = (b << BSH) + t;
        if (rr < N)
            rl[rr] = (unsigned)bse[t] | ((unsigned)(cur[t] - bse[t]) << 13);
    }

    // Phase B: per-receiver gather
    int g = t >> 3, j = t & 7;
    int r = (b << BSH) + g;
    bool active = r < N;
    int k0 = bse[g], k1 = cur[g];
    const __half2 zero2 = __floats2half2_rn(0.f, 0.f);
    __half2 acc01 = zero2, acc23 = zero2;
    int lanebase = (t & 63) & ~7;
    for (int k = k0; k < k1; k += 8) {
        int idx = k + j;
        int s = 0, mk2 = 0;
        if (idx < k1) {
            s = (int)aS[idx];
            unsigned mv = (unsigned)aM[idx];
            mk2 = (int)(mv | (mv << 16));
        }
#pragma unroll
        for (int q8 = 0; q8 < 8; q8++) {
            int st = __shfl(s, lanebase + q8);
            unsigned m2 = (unsigned)__shfl(mk2, lanebase + q8);
            uint2 qv = *((const uint2*)(z16 + 32 * (size_t)st) + j);
            acc01 = __hfma2(uash2(qv.x), uash2(m2), acc01);
            acc23 = __hfma2(uash2(qv.y), uash2(m2), acc23);
        }
    }
    float fa0 = afAcc[g][0], fa1 = afAcc[g][1], fa2 = afAcc[g][2], fa3 = afAcc[g][3];
    if (active && j == 0) {
        uint2 f; f.x = pack2h(fa0, fa1); f.y = pack2h(fa2, fa3);
        F16[r] = f;
    }
    float4 hv = {0.f, 0.f, 0.f, 0.f};
    if (active) {
        float2 a01 = __half22float2(acc01);
        float2 a23 = __half22float2(acc23);
        float4 acc = {a01.x, a01.y, a23.x, a23.y};
        const float* wc = &sWe[4 * j];
        float4 w0 = *(const float4*)(wc);
        float4 w1 = *(const float4*)(wc + HH);
        float4 w2 = *(const float4*)(wc + 2 * HH);
        float4 w3 = *(const float4*)(wc + 3 * HH);
        acc.x += fa0 * w0.x + fa1 * w1.x + fa2 * w2.x + fa3 * w3.x;
        acc.y += fa0 * w0.y + fa1 * w1.y + fa2 * w2.y + fa3 * w3.y;
        acc.z += fa0 * w0.z + fa1 * w1.z + fa2 * w2.z + fa3 * w3.z;
        acc.w += fa0 * w0.w + fa1 * w1.w + fa2 * w2.w + fa3 * w3.w;
        hv.x = fmaxf(acc.x, 0.f);
        hv.y = fmaxf(acc.y, 0.f);
        hv.z = fmaxf(acc.z, 0.f);
        hv.w = fmaxf(acc.w, 0.f);
        rawf4 hvr;
        hvr.x = hv.x; hvr.y = hv.y; hvr.z = hv.z; hvr.w = hv.w;
        __builtin_nontemporal_store(hvr, (rawf4*)(h + 32 * (size_t)r + 4 * j));
    }
#pragma unroll
    for (int off = 8; off < 64; off <<= 1) {
        hv.x += __shfl_xor(hv.x, off);
        hv.y += __shfl_xor(hv.y, off);
        hv.z += __shfl_xor(hv.z, off);
        hv.w += __shfl_xor(hv.w, off);
    }
    if ((t & 63) < 8) {
        atomicAdd(&sp[4 * j + 0], hv.x);
        atomicAdd(&sp[4 * j + 1], hv.y);
        atomicAdd(&sp[4 * j + 2], hv.z);
        atomicAdd(&sp[4 * j + 3], hv.w);
    }
    __syncthreads();
    if (t < HH) unsafeAtomicAdd(&pooled[t], sp[t]);
}

// L1/2 gather: pure streaming. One 8-lane group per receiver; reads the
// grouped gs/gm arrays (written by gather0 into the bA region) directly
// from global, gathers z16, reads cached F16 for the ef part.
__global__ void __launch_bounds__(256)
gather_lite_kernel(const unsigned short* __restrict__ z16,
                   const uint2* __restrict__ bA,   // grouped gs/gm regions
                   const unsigned* __restrict__ rl,
                   const uint2* __restrict__ F16,
                   const float* __restrict__ We,   // [4,32]
                   float* __restrict__ h,
                   float* __restrict__ pooled,
                   int N)
{
    __shared__ float sWe[4 * HH];
    __shared__ float sp[HH];
    if (threadIdx.x < 4 * HH) sWe[threadIdx.x] = We[threadIdx.x];
    if (threadIdx.x < HH) sp[threadIdx.x] = 0.0f;
    __syncthreads();
    int tid = blockIdx.x * blockDim.x + threadIdx.x;
    int v = tid >> 3, j = tid & 7;
    bool active = v < N;
    int lo = 0, k1 = 0;
    const unsigned* gsb = 0;
    const unsigned short* gmb = 0;
    if (active) {
        unsigned w = rl[v];
        lo = (int)(w & 8191u);
        k1 = lo + (int)((w >> 13) & 8191u);
        int b = v >> BSH;
        gsb = (const unsigned*)(bA + (size_t)b * P2CAP);
        gmb = (const unsigned short*)((const char*)(bA + (size_t)b * P2CAP) + 4 * P2CAP);
    }
    const __half2 zero2 = __floats2half2_rn(0.f, 0.f);
    __half2 acc01 = zero2, acc23 = zero2;
    int lanebase = (threadIdx.x & 63) & ~7;
    for (int k = lo; k < k1; k += 8) {
        int idx = k + j;
        int s = 0, mk2 = 0;
        if (idx < k1) {
            unsigned sv = gsb[idx];
            unsigned mv = (unsigned)gmb[idx];
            s = (int)(sv & 0xFFFFF);
            mk2 = (int)(mv | (mv << 16));
        }
#pragma unroll
        for (int q8 = 0; q8 < 8; q8++) {
            int st = __shfl(s, lanebase + q8);
            unsigned m2 = (unsigned)__shfl(mk2, lanebase + q8);
            uint2 qv = *((const uint2*)(z16 + 32 * (size_t)st) + j);
            acc01 = __hfma2(uash2(qv.x), uash2(m2), acc01);
            acc23 = __hfma2(uash2(qv.y), uash2(m2), acc23);
        }
    }
    float4 hv = {0.f, 0.f, 0.f, 0.f};
    if (active) {
        uint2 f = F16[v];
        float2 f01 = __half22float2(uash2(f.x));
        float2 f23 = __half22float2(uash2(f.y));
        float2 a01 = __half22float2(acc01);
        float2 a23 = __half22float2(acc23);
        float4 acc = {a01.x, a01.y, a23.x, a23.y};
        const float* wc = &sWe[4 * j];
        float4 w0 = *(const float4*)(wc);
        float4 w1 = *(const float4*)(wc + HH);
        float4 w2 = *(const float4*)(wc + 2 * HH);
        float4 w3 = *(const float4*)(wc + 3 * HH);
        acc.x += f01.x * w0.x + f01.y * w1.x + f23.x * w2.x + f23.y * w3.x;
        acc.y += f01.x * w0.y + f01.y * w1.y + f23.x * w2.y + f23.y * w3.y;
        acc.z += f01.x * w0.z + f01.y * w1.z + f23.x * w2.z + f23.y * w3.z;
        acc.w += f01.x * w0.w + f01.y * w1.w + f23.x * w2.w + f23.y * w3.w;
        hv.x = fmaxf(acc.x, 0.f);
        hv.y = fmaxf(acc.y, 0.f);
        hv.z = fmaxf(acc.z, 0.f);
        hv.w = fmaxf(acc.w, 0.f);
        rawf4 hvr;
        hvr.x = hv.x; hvr.y = hv.y; hvr.z = hv.z; hvr.w = hv.w;
        __builtin_nontemporal_store(hvr, (rawf4*)(h + 32 * (size_t)v + 4 * j));
    }
#pragma unroll
    for (int off = 8; off < 64; off <<= 1) {
        hv.x += __shfl_xor(hv.x, off);
        hv.y += __shfl_xor(hv.y, off);
        hv.z += __shfl_xor(hv.z, off);
        hv.w += __shfl_xor(hv.w, off);
    }
    if ((threadIdx.x & 63) < 8) {
        atomicAdd(&sp[4 * j + 0], hv.x);
        atomicAdd(&sp[4 * j + 1], hv.y);
        atomicAdd(&sp[4 * j + 2], hv.z);
        atomicAdd(&sp[4 * j + 3], hv.w);
    }
    __syncthreads();
    if (threadIdx.x < HH) unsafeAtomicAdd(&pooled[threadIdx.x], sp[threadIdx.x]);
}

// ---------------- single-pass padded build (path 1 fallback) ----------------

__global__ void build1_kernel(const int* __restrict__ snd, const int* __restrict__ rcv,
                              const float* __restrict__ mask, const float* __restrict__ ef,
                              int* __restrict__ slot, int cap,
                              float4* __restrict__ records, int E)
{
    int e = blockIdx.x * blockDim.x + threadIdx.x;
    if (e >= E) return;
    int r = rcv[e];
    int t = atomicAdd(&slot[r], 1);
    if (t >= cap) return;
    size_t pos = (size_t)cap * r + t;
    int s = snd[e];
    float mk = mask[e];
    float4 f = *(const float4*)(ef + 4 * (size_t)e);
    float4 rec;
    rec.x = __int_as_float(s);
    rec.y = mk;
    rec.z = __uint_as_float(pack2h(mk * f.x, mk * f.y));
    rec.w = __uint_as_float(pack2h(mk * f.z, mk * f.w));
    records[pos] = rec;
}

// ---------------- exact-CSR fallback (path 0) ----------------

__global__ void hist_kernel(const int* __restrict__ rcv, int* __restrict__ deg, int E)
{
    int e = blockIdx.x * blockDim.x + threadIdx.x;
    if (e < E) atomicAdd(&deg[rcv[e]], 1);
}

__global__ void block_sum_kernel(const int* __restrict__ deg, int* __restrict__ bsum, int N)
{
    __shared__ int s[256];
    int i = blockIdx.x * 256 + threadIdx.x;
    s[threadIdx.x] = (i < N) ? deg[i] : 0;
    __syncthreads();
    for (int off = 128; off > 0; off >>= 1) {
        if (threadIdx.x < off) s[threadIdx.x] += s[threadIdx.x + off];
        __syncthreads();
    }
    if (threadIdx.x == 0) bsum[blockIdx.x] = s[0];
}

__global__ void scan_bsum_kernel(const int* __restrict__ bsum, int* __restrict__ boff, int NB)
{
    __shared__ int s[512];
    int t = threadIdx.x;
    int v = (t < NB) ? bsum[t] : 0;
    s[t] = v;
    __syncthreads();
    for (int off = 1; off < 512; off <<= 1) {
        int x = (t >= off) ? s[t - off] : 0;
        __syncthreads();
        s[t] += x;
        __syncthreads();
    }
    if (t < NB) boff[t] = s[t] - v;
}

__global__ void local_scan_kernel(const int* __restrict__ deg, const int* __restrict__ boff,
                                  int* __restrict__ row_start, int* __restrict__ off, int N)
{
    __shared__ int s[256];
    int i = blockIdx.x * 256 + threadIdx.x;
    int v = (i < N) ? deg[i] : 0;
    s[threadIdx.x] = v;
    __syncthreads();
    for (int o = 1; o < 256; o <<= 1) {
        int x = (threadIdx.x >= o) ? s[threadIdx.x - o] : 0;
        __syncthreads();
        s[threadIdx.x] += x;
        __syncthreads();
    }
    if (i < N) {
        int r = boff[blockIdx.x] + s[threadIdx.x] - v;
        row_start[i] = r;
        off[i] = r;
    }
}

__global__ void build0_kernel(const int* __restrict__ snd, const int* __restrict__ rcv,
                              const float* __restrict__ mask, const float* __restrict__ ef,
                              int* __restrict__ slot,
                              float4* __restrict__ records, int E)
{
    int e = blockIdx.x * blockDim.x + threadIdx.x;
    if (e >= E) return;
    int r = rcv[e];
    int t = atomicAdd(&slot[r], 1);
    int s = snd[e];
    float mk = mask[e];
    float4 f = *(const float4*)(ef + 4 * (size_t)e);
    float4 rec;
    rec.x = __int_as_float(s);
    rec.y = mk;
    rec.z = __uint_as_float(pack2h(mk * f.x, mk * f.y));
    rec.w = __uint_as_float(pack2h(mk * f.z, mk * f.w));
    records[(size_t)t] = rec;
}

// ---------------- node-side kernels ----------------

__global__ void init_z_kernel(const float* __restrict__ P,
                              const float* __restrict__ W_in,
                              const float* __restrict__ b_in,
                              const float* __restrict__ Wm,   // [38,32] layer 0
                              const float* __restrict__ bm,
                              float* __restrict__ h,
                              unsigned short* __restrict__ z16,
                              float* __restrict__ V,
                              int N8)
{
    __shared__ float sW[34 * HH];
    __shared__ float sWin[2 * HH];
    __shared__ float sbin[HH];
    __shared__ float sbm[HH];
    for (int i = threadIdx.x; i < 34 * HH; i += blockDim.x) sW[i] = Wm[i];
    if (threadIdx.x < 2 * HH) sWin[threadIdx.x] = W_in[threadIdx.x];
    if (threadIdx.x < HH) { sbin[threadIdx.x] = b_in[threadIdx.x]; sbm[threadIdx.x] = bm[threadIdx.x]; }
    __syncthreads();
    int tid = blockIdx.x * blockDim.x + threadIdx.x;
    if (tid >= N8) return;
    int v = tid >> 3, j = tid & 7;
    float2 p = *(const float2*)(P + 2 * (size_t)v);
    float4 w0 = *(const float4*)&sWin[4 * j];
    float4 w1 = *(const float4*)&sWin[HH + 4 * j];
    float4 b  = *(const float4*)&sbin[4 * j];
    float4 hv;
    hv.x = b.x + p.x * w0.x + p.y * w1.x;
    hv.y = b.y + p.x * w0.y + p.y * w1.y;
    hv.z = b.z + p.x * w0.z + p.y * w1.z;
    hv.w = b.w + p.x * w0.w + p.y * w1.w;
    *(float4*)(h + 4 * (size_t)tid) = hv;
    if (j == 0) { V[2 * v] = 1.0f; V[2 * v + 1] = 0.0f; }
    float4 acc;
    acc.x = sbm[4 * j + 0] + sW[4 * j + 0];
    acc.y = sbm[4 * j + 1] + sW[4 * j + 1];
    acc.z = sbm[4 * j + 2] + sW[4 * j + 2];
    acc.w = sbm[4 * j + 3] + sW[4 * j + 3];
    int base = (threadIdx.x & 63) & ~7;
#pragma unroll
    for (int t = 0; t < 8; t++) {
        float hx = __shfl(hv.x, base + t);
        float hy = __shfl(hv.y, base + t);
        float hz = __shfl(hv.z, base + t);
        float hw = __shfl(hv.w, base + t);
        const float* wr = &sW[(2 + 4 * t) * HH + 4 * j];
        float4 q0 = *(const float4*)(wr);
        float4 q1 = *(const float4*)(wr + HH);
        float4 q2 = *(const float4*)(wr + 2 * HH);
        float4 q3 = *(const float4*)(wr + 3 * HH);
        acc.x += hx * q0.x + hy * q1.x + hz * q2.x + hw * q3.x;
        acc.y += hx * q0.y + hy * q1.y + hz * q2.y + hw * q3.y;
        acc.z += hx * q0.z + hy * q1.z + hz * q2.z + hw * q3.z;
        acc.w += hx * q0.w + hy * q1.w + hz * q2.w + hw * q3.w;
    }
    uint2 q;
    q.x = pack2h(acc.x, acc.y);
    q.y = pack2h(acc.z, acc.w);
    *((uint2*)(z16 + 32 * (size_t)v) + j) = q;
}

// classic pull-gather (fallback paths 0/1; reads padded/CSR records)
__global__ void __launch_bounds__(256)
gather_kernel(const unsigned short* __restrict__ z16,
              const int* __restrict__ row_start,
              const int* __restrict__ cnt,
              int cap,
              const float4* __restrict__ records,
              const float* __restrict__ We,   // [4,32]
              float* __restrict__ h,
              float* __restrict__ pooled,
              int N)
{
    __shared__ float sWe[4 * HH];
    __shared__ float sp[HH];
    if (threadIdx.x < 4 * HH) sWe[threadIdx.x] = We[threadIdx.x];
    if (threadIdx.x < HH) sp[threadIdx.x] = 0.0f;
    __syncthreads();
    int tid = blockIdx.x * blockDim.x + threadIdx.x;
    int v = tid >> 3, j = tid & 7;
    bool active = v < N;
    int k0 = 0, k1 = 0;
    if (active) {
        int len = cnt[v];
        if (cap > 0) {
            if (len > cap) len = cap;
            k0 = cap * v;
        } else {
            k0 = row_start[v];
        }
        k1 = k0 + len;
    }
    const __half2 zero2 = __floats2half2_rn(0.f, 0.f);
    __half2 acc01 = zero2, acc23 = zero2;
    __half2 af01 = zero2, af23 = zero2;
    int base = (threadIdx.x & 63) & ~7;
    const rawf4* recs = (const rawf4*)records;
    rawf4 rn = {0.f, 0.f, 0.f, 0.f};
    if (k0 + j < k1) rn = __builtin_nontemporal_load(&recs[(size_t)(k0 + j)]);
    for (int k = k0; k < k1; k += 8) {
        rawf4 r0 = rn;
        rn.x = 0.f; rn.y = 0.f; rn.z = 0.f; rn.w = 0.f;
        int kn = k + 8 + j;
        if (kn < k1) rn = __builtin_nontemporal_load(&recs[(size_t)kn]);
        int s = __float_as_int(r0.x) & 0xFFFFF;
        int mk2 = (int)h2asu(__float2half2_rn(r0.y));
        af01 = __hadd2(af01, uash2(__float_as_uint(r0.z)));
        af23 = __hadd2(af23, uash2(__float_as_uint(r0.w)));
#pragma unroll
        for (int t = 0; t < 8; t++) {
            int st = __shfl(s, base + t);
            unsigned m2 = (unsigned)__shfl(mk2, base + t);
            uint2 q = *((const uint2*)(z16 + 32 * (size_t)st) + j);
            acc01 = __hfma2(uash2(q.x), uash2(m2), acc01);
            acc23 = __hfma2(uash2(q.y), uash2(m2), acc23);
        }
    }
#pragma unroll
    for (int off = 1; off < 8; off <<= 1) {
        af01 = __hadd2(af01, uash2((unsigned)__shfl_xor((int)h2asu(af01), off)));
        af23 = __hadd2(af23, uash2((unsigned)__shfl_xor((int)h2asu(af23), off)));
    }
    float4 hv = {0.f, 0.f, 0.f, 0.f};
    if (active) {
        float2 a01 = __half22float2(acc01);
        float2 a23 = __half22float2(acc23);
        float2 f01 = __half22float2(af01);
        float2 f23 = __half22float2(af23);
        float4 acc = {a01.x, a01.y, a23.x, a23.y};
        const float* wc = &sWe[4 * j];
        float4 w0 = *(const float4*)(wc);
        float4 w1 = *(const float4*)(wc + HH);
        float4 w2 = *(const float4*)(wc + 2 * HH);
        float4 w3 = *(const float4*)(wc + 3 * HH);
        acc.x += f01.x * w0.x + f01.y * w1.x + f23.x * w2.x + f23.y * w3.x;
        acc.y += f01.x * w0.y + f01.y * w1.y + f23.x * w2.y + f23.y * w3.y;
        acc.z += f01.x * w0.z + f01.y * w1.z + f23.x * w2.z + f23.y * w3.z;
        acc.w += f01.x * w0.w + f01.y * w1.w + f23.x * w2.w + f23.y * w3.w;
        hv.x = fmaxf(acc.x, 0.f);
        hv.y = fmaxf(acc.y, 0.f);
        hv.z = fmaxf(acc.z, 0.f);
        hv.w = fmaxf(acc.w, 0.f);
        *(float4*)(h + 4 * (size_t)tid) = hv;
    }
#pragma unroll
    for (int off = 8; off < 64; off <<= 1) {
        hv.x += __shfl_xor(hv.x, off);
        hv.y += __shfl_xor(hv.y, off);
        hv.z += __shfl_xor(hv.z, off);
        hv.w += __shfl_xor(hv.w, off);
    }
    if ((threadIdx.x & 63) < 8) {
        atomicAdd(&sp[4 * j + 0], hv.x);
        atomicAdd(&sp[4 * j + 1], hv.y);
        atomicAdd(&sp[4 * j + 2], hv.z);
        atomicAdd(&sp[4 * j + 3], hv.w);
    }
    __syncthreads();
    if (threadIdx.x < HH) unsafeAtomicAdd(&pooled[threadIdx.x], sp[threadIdx.x]);
}

// fused: g update + node update + next-layer z16
__global__ void update_kernel(const float* __restrict__ h,
                              const float* __restrict__ g_in,
                              float* __restrict__ g_out,
                              const float* __restrict__ pooled,
                              float invN,
                              const float* __restrict__ Wg,
                              const float* __restrict__ bg,
                              const float* __restrict__ Wn,
                              const float* __restrict__ bn,
                              const float* __restrict__ Wout,
                              const float* __restrict__ bout,
                              float* __restrict__ V,
                              const float* __restrict__ Wm,
                              const float* __restrict__ bm,
                              unsigned short* __restrict__ z16,
                              int has_next,
                              int N8)
{
    __shared__ float sWn[64 * HH];
    __shared__ float sWm[34 * HH];
    __shared__ float sgnew[HH];
    __shared__ float sgp[64];
    __shared__ float sWo[HH * 2];
    __shared__ float sb[2 * HH + 2];
    for (int i = threadIdx.x; i < 64 * HH; i += blockDim.x) sWn[i] = Wn[i];
    if (has_next)
        for (int i = threadIdx.x; i < 34 * HH; i += blockDim.x) sWm[i] = Wm[i];
    if (threadIdx.x < 64)
        sgp[threadIdx.x] = (threadIdx.x < HH) ? g_in[threadIdx.x]
                                              : pooled[threadIdx.x - HH] * invN;
    if (threadIdx.x < HH * 2) sWo[threadIdx.x] = Wout[threadIdx.x];
    if (threadIdx.x < HH) sb[threadIdx.x] = bn[threadIdx.x];
    if (threadIdx.x < 2) sb[2 * HH + threadIdx.x] = bout[threadIdx.x];
    if (has_next && threadIdx.x >= 64 && threadIdx.x < 64 + HH)
        sb[HH + threadIdx.x - 64] = bm[threadIdx.x - 64];
    __syncthreads();
    if (threadIdx.x < HH) {
        int k = threadIdx.x;
        float acc = bg[k];
#pragma unroll 8
        for (int i = 0; i < 64; i++) acc += sgp[i] * Wg[i * HH + k];
        sgnew[k] = fmaxf(acc, 0.f);
    }
    __syncthreads();
    if (blockIdx.x == 0 && threadIdx.x < HH) g_out[threadIdx.x] = sgnew[threadIdx.x];

    int tid = blockIdx.x * blockDim.x + threadIdx.x;
    if (tid >= N8) return;
    int v = tid >> 3, j = tid & 7;
    float4 hv = *(const float4*)(h + 4 * (size_t)tid);
    float4 acc;
    acc.x = sb[4 * j + 0]; acc.y = sb[4 * j + 1];
    acc.z = sb[4 * j + 2]; acc.w = sb[4 * j + 3];
#pragma unroll 8
    for (int i = 0; i < HH; i++) {
        float gi = sgnew[i];
        const float4 w = *(const float4*)&sWn[(HH + i) * HH + 4 * j];
        acc.x += gi * w.x; acc.y += gi * w.y;
        acc.z += gi * w.z; acc.w += gi * w.w;
    }
    int base = (threadIdx.x & 63) & ~7;
#pragma unroll
    for (int t = 0; t < 8; t++) {
        float hx = __shfl(hv.x, base + t);
        float hy = __shfl(hv.y, base + t);
        float hz = __shfl(hv.z, base + t);
        float hw = __shfl(hv.w, base + t);
        const float* wr = &sWn[(4 * t) * HH + 4 * j];
        float4 q0 = *(const float4*)(wr);
        float4 q1 = *(const float4*)(wr + HH);
        float4 q2 = *(const float4*)(wr + 2 * HH);
        float4 q3 = *(const float4*)(wr + 3 * HH);
        acc.x += hx * q0.x + hy * q1.x + hz * q2.x + hw * q3.x;
        acc.y += hx * q0.y + hy * q1.y + hz * q2.y + hw * q3.y;
        acc.z += hx * q0.z + hy * q1.z + hz * q2.z + hw * q3.z;
        acc.w += hx * q0.w + hy * q1.w + hz * q2.w + hw * q3.w;
    }
    float4 hn;
    hn.x = fmaxf(acc.x, 0.f);
    hn.y = fmaxf(acc.y, 0.f);
    hn.z = fmaxf(acc.z, 0.f);
    hn.w = fmaxf(acc.w, 0.f);
    float p0 = hn.x * sWo[(4 * j + 0) * 2 + 0] + hn.y * sWo[(4 * j + 1) * 2 + 0]
             + hn.z * sWo[(4 * j + 2) * 2 + 0] + hn.w * sWo[(4 * j + 3) * 2 + 0];
    float p1 = hn.x * sWo[(4 * j + 0) * 2 + 1] + hn.y * sWo[(4 * j + 1) * 2 + 1]
             + hn.z * sWo[(4 * j + 2) * 2 + 1] + hn.w * sWo[(4 * j + 3) * 2 + 1];
#pragma unroll
    for (int off = 1; off < 8; off <<= 1) {
        p0 += __shfl_xor(p0, off);
        p1 += __shfl_xor(p1, off);
    }
    float2 Vold = *(const float2*)(V + 2 * v);
    float2 Vnew;
    Vnew.x = Vold.x + p0 + sb[2 * HH + 0];
    Vnew.y = Vold.y + p1 + sb[2 * HH + 1];
    if (j == 0) *(float2*)(V + 2 * v) = Vnew;
    if (!has_next) return;
    float4 az;
    az.x = sb[HH + 4 * j + 0] + Vnew.x * sWm[4 * j + 0] + Vnew.y * sWm[HH + 4 * j + 0];
    az.y = sb[HH + 4 * j + 1] + Vnew.x * sWm[4 * j + 1] + Vnew.y * sWm[HH + 4 * j + 1];
    az.z = sb[HH + 4 * j + 2] + Vnew.x * sWm[4 * j + 2] + Vnew.y * sWm[HH + 4 * j + 2];
    az.w = sb[HH + 4 * j + 3] + Vnew.x * sWm[4 * j + 3] + Vnew.y * sWm[HH + 4 * j + 3];
#pragma unroll
    for (int t = 0; t < 8; t++) {
        float hx = __shfl(hn.x, base + t);
        float hy = __shfl(hn.y, base + t);
        float hz = __shfl(hn.z, base + t);
        float hw = __shfl(hn.w, base + t);
        const float* wr = &sWm[(2 + 4 * t) * HH + 4 * j];
        float4 q0 = *(const float4*)(wr);
        float4 q1 = *(const float4*)(wr + HH);
        float4 q2 = *(const float4*)(wr + 2 * HH);
        float4 q3 = *(const float4*)(wr + 3 * HH);
        az.x += hx * q0.x + hy * q1.x + hz * q2.x + hw * q3.x;
        az.y += hx * q0.y + hy * q1.y + hz * q2.y + hw * q3.y;
        az.z += hx * q0.z + hy * q1.z + hz * q2.z + hw * q3.z;
        az.w += hx * q0.w + hy * q1.w + hz * q2.w + hw * q3.w;
    }
    uint2 q;
    q.x = pack2h(az.x, az.y);
    q.y = pack2h(az.z, az.w);
    *((uint2*)(z16 + 32 * (size_t)v) + j) = q;
}

extern "C" void kernel_launch(void* const* d_in, const int* in_sizes, int n_in,
                              void* d_out, int out_size, void* d_ws, size_t ws_size,
                              hipStream_t stream)
{
    const float* P     = (const float*)d_in[0];
    const int*   snd   = (const int*)d_in[1];
    const int*   rcv   = (const int*)d_in[2];
    const float* ef    = (const float*)d_in[3];
    const float* mask  = (const float*)d_in[4];
    const float* W_in  = (const float*)d_in[5];
    const float* b_in  = (const float*)d_in[6];
    const float* W_msg = (const float*)d_in[7];
    const float* b_msg = (const float*)d_in[8];
    const float* W_g   = (const float*)d_in[9];
    const float* b_g   = (const float*)d_in[10];
    const float* W_n   = (const float*)d_in[11];
    const float* b_n   = (const float*)d_in[12];
    const float* W_out = (const float*)d_in[13];
    const float* b_out = (const float*)d_in[14];
    float* V = (float*)d_out;

    const int N = in_sizes[0] / 2;
    const int E = in_sizes[1];
    const int N8 = N * 8;
    const int NB = (N + 255) / 256;
    const int nbuck = (N + (1 << BSH) - 1) >> BSH;   // <= 1024 for N<=131072

    dim3 blk(256);
    int gn = (N8 + 255) / 256;
    int ge = (E + 255) / 256;
    int g1 = (E + P1_EPB - 1) / P1_EPB;

    // path-2 eligibility: partition capacity fits the compile-time LDS cap
    long long bexp = ((long long)E << BSH) / (N > 0 ? N : 1);
    int need = (int)((double)bexp + 10.0 * sqrt((double)bexp) + 64.0);
    size_t p2bytes = (size_t)nbuck * P2CAP * 16          // bA + bB
                   + 128ull * (size_t)N                  // h
                   + 64ull * (size_t)N                   // z16
                   + 8ull * (size_t)N                    // F16
                   + 4ull * (size_t)N                    // rl
                   + 4ull * (MAXB + 7 * HH) + 4096;
    bool p2ok = (need <= P2CAP) && (nbuck <= MAXB) && (N < (1 << 20)) &&
                (ws_size >= p2bytes);

    if (p2ok) {
        uint2* bA = (uint2*)d_ws;
        uint2* bB = bA + (size_t)nbuck * P2CAP;
        float* h = (float*)(bB + (size_t)nbuck * P2CAP);
        unsigned short* z16 = (unsigned short*)(h + (size_t)N * HH);
        uint2* F16 = (uint2*)(z16 + (size_t)N * HH);
        unsigned* rl = (unsigned*)(F16 + N);
        int* tail = (int*)(rl + N);
        float* pooled = (float*)(tail + MAXB);
        float* g_buf = pooled + 3 * HH;
        (void)hipMemsetAsync(tail, 0, (MAXB + 7 * HH) * sizeof(int), stream);
        pass1_bin_kernel<<<g1, dim3(P1_TPB), 0, stream>>>(snd, rcv, mask, ef, tail,
                                                          bA, bB, E, nbuck, P2CAP);
        init_z_kernel<<<gn, blk, 0, stream>>>(P, W_in, b_in, W_msg, b_msg, h, z16, V, N8);
        for (int l = 0; l < 3; l++) {
            const float* Wm = W_msg + (size_t)l * 38 * HH;
            const float* Wm_next = W_msg + (size_t)(l + 1) * 38 * HH;
            if (l == 0)
                gather0_kernel<<<nbuck, dim3(1024), 0, stream>>>(
                    z16, tail, bA, bB, Wm + 34 * HH, h, F16, rl, pooled + l * HH, N);
            else
                gather_lite_kernel<<<gn, blk, 0, stream>>>(
                    z16, bA, rl, F16, Wm + 34 * HH, h, pooled + l * HH, N);
            update_kernel<<<gn, blk, 0, stream>>>(h, g_buf + l * HH, g_buf + (l + 1) * HH,
                                                  pooled + l * HH, 1.0f / (float)N,
                                                  W_g + (size_t)l * 64 * HH, b_g + l * HH,
                                                  W_n + (size_t)l * 64 * HH, b_n + l * HH,
                                                  W_out + (size_t)l * HH * 2, b_out + l * 2,
                                                  V,
                                                  (l < 2) ? Wm_next : Wm,
                                                  (l < 2) ? (b_msg + (l + 1) * HH) : (b_msg + l * HH),
                                                  z16, (l < 2) ? 1 : 0, N8);
        }
        return;
    }

    // ---------------- fallback paths (padded / exact CSR) ----------------
    size_t fixed = 128 * (size_t)N + 64 * (size_t)N + 4 * (size_t)N
                 + 4 * (MAXB + 7 * HH) + 4096;
    size_t avail = (ws_size > fixed) ? ws_size - fixed : 0;
    int path, cap = 0;
    {
        long cap1 = (long)(avail / (16 * (size_t)N));
        if (cap1 >= 72) { path = 1; cap = (cap1 > 96) ? 96 : (int)cap1; }
        else             path = 0;
    }

    if (path == 1) {
        float4* records = (float4*)d_ws;
        float*  h       = (float*)(records + (size_t)cap * N);
        unsigned short* z16 = (unsigned short*)(h + (size_t)N * HH);
        int* cnt        = (int*)(z16 + (size_t)N * HH);
        float* pooled   = (float*)(cnt + N);
        float* g_buf    = pooled + 3 * HH;
        (void)hipMemsetAsync(cnt, 0, ((size_t)N + 7 * HH) * sizeof(int), stream);
        build1_kernel<<<ge, blk, 0, stream>>>(snd, rcv, mask, ef, cnt, cap, records, E);
        init_z_kernel<<<gn, blk, 0, stream>>>(P, W_in, b_in, W_msg, b_msg, h, z16, V, N8);
        for (int l = 0; l < 3; l++) {
            const float* Wm = W_msg + (size_t)l * 38 * HH;
            const float* Wm_next = W_msg + (size_t)(l + 1) * 38 * HH;
            gather_kernel<<<gn, blk, 0, stream>>>(z16, cnt, cnt, cap, records,
                                                  Wm + 34 * HH, h, pooled + l * HH, N);
            update_kernel<<<gn, blk, 0, stream>>>(h, g_buf + l * HH, g_buf + (l + 1) * HH,
                                                  pooled + l * HH, 1.0f / (float)N,
                                                  W_g + (size_t)l * 64 * HH, b_g + l * HH,
                                                  W_n + (size_t)l * 64 * HH, b_n + l * HH,
                                                  W_out + (size_t)l * HH * 2, b_out + l * 2,
                                                  V,
                                                  (l < 2) ? Wm_next : Wm,
                                                  (l < 2) ? (b_msg + (l + 1) * HH) : (b_msg + l * HH),
                                                  z16, (l < 2) ? 1 : 0, N8);
        }
    } else {
        float4* records  = (float4*)d_ws;
        float*  h        = (float*)(records + (size_t)E);
        unsigned short* z16 = (unsigned short*)(h + (size_t)N * HH);
        int* cnt         = (int*)(z16 + (size_t)N * HH);
        int* row_start   = cnt + N;
        int* off         = row_start + (N + 1);
        int* bsum        = off + N;
        int* boff        = bsum + 512;
        float* pooled    = (float*)(boff + 512);
        float* g_buf     = pooled + 3 * HH;
        (void)hipMemsetAsync(cnt, 0, ((size_t)(3 * N + 1 + 1024) + 7 * HH) * sizeof(int), stream);
        hist_kernel<<<ge, blk, 0, stream>>>(rcv, cnt, E);
        block_sum_kernel<<<NB, blk, 0, stream>>>(cnt, bsum, N);
        scan_bsum_kernel<<<1, 512, 0, stream>>>(bsum, boff, NB);
        local_scan_kernel<<<NB, blk, 0, stream>>>(cnt, boff, row_start, off, N);
        build0_kernel<<<ge, blk, 0, stream>>>(snd, rcv, mask, ef, off, records, E);
        init_z_kernel<<<gn, blk, 0, stream>>>(P, W_in, b_in, W_msg, b_msg, h, z16, V, N8);
        for (int l = 0; l < 3; l++) {
            const float* Wm = W_msg + (size_t)l * 38 * HH;
            const float* Wm_next = W_msg + (size_t)(l + 1) * 38 * HH;
            gather_kernel<<<gn, blk, 0, stream>>>(z16, row_start, cnt, 0, records,
                                                  Wm + 34 * HH, h, pooled + l * HH, N);
            update_kernel<<<gn, blk, 0, stream>>>(h, g_buf + l * HH, g_buf + (l + 1) * HH,
                                                  pooled + l * HH, 1.0f / (float)N,
                                                  W_g + (size_t)l * 64 * HH, b_g + l * HH,
                                                  W_n + (size_t)l * 64 * HH, b_n + l * HH,
                                                  W_out + (size_t)l * HH * 2, b_out + l * 2,
                                                  V,
                                                  (l < 2) ? Wm_next : Wm,
                                                  (l < 2) ? (b_msg + (l + 1) * HH) : (b_msg + l * HH),
                                                  z16, (l < 2) ? 1 : 0, N8);
        }
    }
}

// Round 9
// 441.514 us; speedup vs baseline: 1.2119x; 1.2119x over previous
//
#include <hip/hip_runtime.h>
#include <hip/hip_fp16.h>
#include <math.h>

// GNN power-flow forward. N=100k, E=3.2M, H=32, L=3, FE=4.
// R19 == exact R15 resubmission (bisect). R17/R18 (3-plane records) failed
// twice with "container failed twice" and no counters; this source ran at
// 439.4us in Round 5. If it passes now, the 3-plane delta is implicated;
// if it fails, the infra outage is confirmed and the kernel is exonerated.
// R15: eliminate pass2 + cache the layer-invariant ef reduction.
//  - records split SoA: A = {s|rloc, mask_f32} 8B, B = premult ef halves 8B.
//  - F16[v] = sum(mask*ef) cached by layer-0 gather; layers 1-2 read A only
//    and skip the af accumulation.
//  - gather_part blocks (1 per 128-rcv partition, BSH=7) stage the
//    partition's A-records in LDS, group them by receiver via LDS
//    hist+scan+scatter, then run the 8-lane-per-receiver gather loop.
//  - L0 variant stages B too (80KB LDS); L1/2 variant 42KB LDS.

#define HH 32        // hidden dim
#define BSH 7        // bucket shift: 128 receivers per partition
#define MAXB 1024    // max partitions (N <= 131072)
#define P2CAP 4992   // fixed per-partition record capacity (path 2)
#define P1_TPB 1024  // pass1 threads per block
#define P1_EPT 8     // pass1 edges per thread
#define P1_EPB (P1_TPB * P1_EPT)   // 8192 edges per block

typedef float rawf4 __attribute__((ext_vector_type(4)));

__device__ __forceinline__ unsigned pack2h(float a, float b) {
    return ((unsigned)__half_as_ushort(__float2half_rn(b)) << 16) |
           (unsigned)__half_as_ushort(__float2half_rn(a));
}
__device__ __forceinline__ __half2 uash2(unsigned u) {
    return *reinterpret_cast<__half2*>(&u);
}
__device__ __forceinline__ unsigned h2asu(__half2 h) {
    return *reinterpret_cast<unsigned*>(&h);
}

// ---------------- build (path 2) ----------------

// pass 1: block-local LDS binning. 8192 edges/block -> LDS hist over
// partitions -> LDS scan -> one global reservation per partition ->
// scatter records into LDS -> coalesced SoA copy-out (A + B arrays).
__global__ void __launch_bounds__(P1_TPB)
pass1_bin_kernel(const int* __restrict__ snd, const int* __restrict__ rcv,
                 const float* __restrict__ mask, const float* __restrict__ ef,
                 int* __restrict__ tail,
                 uint2* __restrict__ bA, uint2* __restrict__ bB,
                 int E, int nbuck, int bcap)
{
    __shared__ float4 srec[P1_EPB];            // 128KB
    __shared__ unsigned short sbid[P1_EPB];    // 16KB
    __shared__ int cur[MAXB];
    __shared__ int dlt[MAXB];
    int lo = blockIdx.x * P1_EPB;
    int n = E - lo; if (n > P1_EPB) n = P1_EPB;
    int t = threadIdx.x;

    for (int i = t; i < MAXB; i += P1_TPB) cur[i] = 0;
    __syncthreads();

    int rv[P1_EPT];
#pragma unroll
    for (int i = 0; i < P1_EPT; i++) {
        int e = lo + t + i * P1_TPB;
        int r = (e < E) ? rcv[e] : -1;
        rv[i] = r;
        if (r >= 0) atomicAdd(&cur[r >> BSH], 1);
    }
    __syncthreads();

    int v = (t < nbuck) ? cur[t] : 0;
    dlt[t] = v;
    __syncthreads();
    for (int off = 1; off < P1_TPB; off <<= 1) {
        int x = (t >= off) ? dlt[t - off] : 0;
        __syncthreads();
        dlt[t] += x;
        __syncthreads();
    }
    int lstart = dlt[t] - v;
    int gbase = 0;
    if (t < nbuck && v > 0) gbase = atomicAdd(&tail[t], v);
    __syncthreads();
    cur[t] = lstart;
    dlt[t] = gbase - lstart;
    __syncthreads();

#pragma unroll
    for (int i = 0; i < P1_EPT; i++) {
        int r = rv[i];
        if (r < 0) continue;
        int e = lo + t + i * P1_TPB;
        int b = r >> BSH;
        int pos = atomicAdd(&cur[b], 1);
        int s = snd[e];
        float mk = mask[e];
        float4 f = *(const float4*)(ef + 4 * (size_t)e);
        float4 rec;
        rec.x = __int_as_float(s | ((r & ((1 << BSH) - 1)) << 20));
        rec.y = mk;
        rec.z = __uint_as_float(pack2h(mk * f.x, mk * f.y));
        rec.w = __uint_as_float(pack2h(mk * f.z, mk * f.w));
        srec[pos] = rec;
        sbid[pos] = (unsigned short)b;
    }
    __syncthreads();

    for (int i = t; i < n; i += P1_TPB) {
        int b = sbid[i];
        unsigned oin = (unsigned)(i + dlt[b]);
        if (oin < (unsigned)bcap) {
            float4 rec = srec[i];
            size_t o = (size_t)b * bcap + oin;
            uint2 a; a.x = __float_as_uint(rec.x); a.y = __float_as_uint(rec.y);
            bA[o] = a;
            uint2 bb; bb.x = __float_as_uint(rec.z); bb.y = __float_as_uint(rec.w);
            bB[o] = bb;
        }
    }
}

// fused group+gather: one block per 128-receiver partition.
// Phase A: LDS hist (lo-word read) -> scan -> scatter A(+B) grouped by rloc.
// Phase B: 128 groups x 8 lanes run the classic z16-gather loop from LDS.
// L0==1: also accumulate af from B and write F16[v]. L0==0: read F16[v].
template<int L0>
__global__ void __launch_bounds__(1024)
gather_part_kernel(const unsigned short* __restrict__ z16,
                   const int* __restrict__ tail,
                   const uint2* __restrict__ bA,
                   const uint2* __restrict__ bB,
                   const float* __restrict__ We,   // [4,32] this layer
                   float* __restrict__ h,
                   uint2* __restrict__ F16,
                   float* __restrict__ pooled,
                   int N)
{
    __shared__ uint2 aG[P2CAP];
    __shared__ uint2 bG[L0 ? P2CAP : 1];
    __shared__ int hist[1 << BSH];
    __shared__ int bse[1 << BSH];
    __shared__ int cur[1 << BSH];
    __shared__ float sWe[4 * HH];
    __shared__ float sp[HH];
    int t = threadIdx.x, b = blockIdx.x;
    if (t < (1 << BSH)) hist[t] = 0;
    if (t < 4 * HH) sWe[t] = We[t];
    if (t < HH) sp[t] = 0.0f;
    __syncthreads();
    int n = tail[b];
    if (n > P2CAP) n = P2CAP;
    if (n < 0) n = 0;
    size_t gb = (size_t)b * P2CAP;

    // A1: histogram by rloc (read lo word only; segment stays L2-hot)
    const unsigned* loA = (const unsigned*)(bA + gb);
    for (int i = t; i < n; i += 1024)
        atomicAdd(&hist[(loA[2 * i] >> 20) & ((1 << BSH) - 1)], 1);
    __syncthreads();

    // A2: exclusive scan over 128 rlocs
    if (t < (1 << BSH)) bse[t] = hist[t];
    __syncthreads();
    for (int off = 1; off < (1 << BSH); off <<= 1) {
        int x = (t < (1 << BSH) && t >= off) ? bse[t - off] : 0;
        __syncthreads();
        if (t < (1 << BSH)) bse[t] += x;
        __syncthreads();
    }
    if (t < (1 << BSH)) { int s0 = bse[t] - hist[t]; bse[t] = s0; cur[t] = s0; }
    __syncthreads();

    // A3: scatter into grouped LDS lists (re-read is L2-hot)
    for (int i = t; i < n; i += 1024) {
        uint2 a = bA[gb + i];
        int rl = (a.x >> 20) & ((1 << BSH) - 1);
        int p = atomicAdd(&cur[rl], 1);
        aG[p] = a;
        if (L0) bG[p] = bB[gb + i];
    }
    __syncthreads();

    // B: per-receiver gather. group g handles receiver (b<<7)+g.
    int g = t >> 3, j = t & 7;
    int r = (b << BSH) + g;
    bool active = r < N;
    int k0 = bse[g], k1 = cur[g];
    const __half2 zero2 = __floats2half2_rn(0.f, 0.f);
    __half2 acc01 = zero2, acc23 = zero2, af01 = zero2, af23 = zero2;
    int lanebase = (t & 63) & ~7;
    for (int k = k0; k < k1; k += 8) {
        int idx = k + j;
        uint2 a; a.x = 0u; a.y = 0u;
        if (idx < k1) a = aG[idx];
        int s = a.x & 0xFFFFF;
        float mk = __uint_as_float(a.y);
        int mk2 = (int)h2asu(__float2half2_rn(mk));
        if (L0) {
            if (idx < k1) {
                uint2 bb = bG[idx];
                af01 = __hadd2(af01, uash2(bb.x));
                af23 = __hadd2(af23, uash2(bb.y));
            }
        }
#pragma unroll
        for (int q8 = 0; q8 < 8; q8++) {
            int st = __shfl(s, lanebase + q8);
            unsigned m2 = (unsigned)__shfl(mk2, lanebase + q8);
            uint2 qv = *((const uint2*)(z16 + 32 * (size_t)st) + j);
            acc01 = __hfma2(uash2(qv.x), uash2(m2), acc01);
            acc23 = __hfma2(uash2(qv.y), uash2(m2), acc23);
        }
    }
    if (L0) {
#pragma unroll
        for (int off = 1; off < 8; off <<= 1) {
            af01 = __hadd2(af01, uash2((unsigned)__shfl_xor((int)h2asu(af01), off)));
            af23 = __hadd2(af23, uash2((unsigned)__shfl_xor((int)h2asu(af23), off)));
        }
        if (active && j == 0) {
            uint2 f; f.x = h2asu(af01); f.y = h2asu(af23);
            F16[r] = f;
        }
    } else {
        if (active) {
            uint2 f = F16[r];
            af01 = uash2(f.x);
            af23 = uash2(f.y);
        }
    }
    float4 hv = {0.f, 0.f, 0.f, 0.f};
    if (active) {
        float2 a01 = __half22float2(acc01);
        float2 a23 = __half22float2(acc23);
        float2 f01 = __half22float2(af01);
        float2 f23 = __half22float2(af23);
        float4 acc = {a01.x, a01.y, a23.x, a23.y};
        const float* wc = &sWe[4 * j];
        float4 w0 = *(const float4*)(wc);
        float4 w1 = *(const float4*)(wc + HH);
        float4 w2 = *(const float4*)(wc + 2 * HH);
        float4 w3 = *(const float4*)(wc + 3 * HH);
        acc.x += f01.x * w0.x + f01.y * w1.x + f23.x * w2.x + f23.y * w3.x;
        acc.y += f01.x * w0.y + f01.y * w1.y + f23.x * w2.y + f23.y * w3.y;
        acc.z += f01.x * w0.z + f01.y * w1.z + f23.x * w2.z + f23.y * w3.z;
        acc.w += f01.x * w0.w + f01.y * w1.w + f23.x * w2.w + f23.y * w3.w;
        hv.x = fmaxf(acc.x, 0.f);
        hv.y = fmaxf(acc.y, 0.f);
        hv.z = fmaxf(acc.z, 0.f);
        hv.w = fmaxf(acc.w, 0.f);
        rawf4 hvr;
        hvr.x = hv.x; hvr.y = hv.y; hvr.z = hv.z; hvr.w = hv.w;
        __builtin_nontemporal_store(hvr, (rawf4*)(h + 32 * (size_t)r + 4 * j));
    }
#pragma unroll
    for (int off = 8; off < 64; off <<= 1) {
        hv.x += __shfl_xor(hv.x, off);
        hv.y += __shfl_xor(hv.y, off);
        hv.z += __shfl_xor(hv.z, off);
        hv.w += __shfl_xor(hv.w, off);
    }
    if ((t & 63) < 8) {
        atomicAdd(&sp[4 * j + 0], hv.x);
        atomicAdd(&sp[4 * j + 1], hv.y);
        atomicAdd(&sp[4 * j + 2], hv.z);
        atomicAdd(&sp[4 * j + 3], hv.w);
    }
    __syncthreads();
    if (t < HH) unsafeAtomicAdd(&pooled[t], sp[t]);
}

// ---------------- single-pass padded build (path 1 fallback) ----------------

__global__ void build1_kernel(const int* __restrict__ snd, const int* __restrict__ rcv,
                              const float* __restrict__ mask, const float* __restrict__ ef,
                              int* __restrict__ slot, int cap,
                              float4* __restrict__ records, int E)
{
    int e = blockIdx.x * blockDim.x + threadIdx.x;
    if (e >= E) return;
    int r = rcv[e];
    int t = atomicAdd(&slot[r], 1);
    if (t >= cap) return;
    size_t pos = (size_t)cap * r + t;
    int s = snd[e];
    float mk = mask[e];
    float4 f = *(const float4*)(ef + 4 * (size_t)e);
    float4 rec;
    rec.x = __int_as_float(s);
    rec.y = mk;
    rec.z = __uint_as_float(pack2h(mk * f.x, mk * f.y));
    rec.w = __uint_as_float(pack2h(mk * f.z, mk * f.w));
    records[pos] = rec;
}

// ---------------- exact-CSR fallback (path 0) ----------------

__global__ void hist_kernel(const int* __restrict__ rcv, int* __restrict__ deg, int E)
{
    int e = blockIdx.x * blockDim.x + threadIdx.x;
    if (e < E) atomicAdd(&deg[rcv[e]], 1);
}

__global__ void block_sum_kernel(const int* __restrict__ deg, int* __restrict__ bsum, int N)
{
    __shared__ int s[256];
    int i = blockIdx.x * 256 + threadIdx.x;
    s[threadIdx.x] = (i < N) ? deg[i] : 0;
    __syncthreads();
    for (int off = 128; off > 0; off >>= 1) {
        if (threadIdx.x < off) s[threadIdx.x] += s[threadIdx.x + off];
        __syncthreads();
    }
    if (threadIdx.x == 0) bsum[blockIdx.x] = s[0];
}

__global__ void scan_bsum_kernel(const int* __restrict__ bsum, int* __restrict__ boff, int NB)
{
    __shared__ int s[512];
    int t = threadIdx.x;
    int v = (t < NB) ? bsum[t] : 0;
    s[t] = v;
    __syncthreads();
    for (int off = 1; off < 512; off <<= 1) {
        int x = (t >= off) ? s[t - off] : 0;
        __syncthreads();
        s[t] += x;
        __syncthreads();
    }
    if (t < NB) boff[t] = s[t] - v;
}

__global__ void local_scan_kernel(const int* __restrict__ deg, const int* __restrict__ boff,
                                  int* __restrict__ row_start, int* __restrict__ off, int N)
{
    __shared__ int s[256];
    int i = blockIdx.x * 256 + threadIdx.x;
    int v = (i < N) ? deg[i] : 0;
    s[threadIdx.x] = v;
    __syncthreads();
    for (int o = 1; o < 256; o <<= 1) {
        int x = (threadIdx.x >= o) ? s[threadIdx.x - o] : 0;
        __syncthreads();
        s[threadIdx.x] += x;
        __syncthreads();
    }
    if (i < N) {
        int r = boff[blockIdx.x] + s[threadIdx.x] - v;
        row_start[i] = r;
        off[i] = r;
    }
}

__global__ void build0_kernel(const int* __restrict__ snd, const int* __restrict__ rcv,
                              const float* __restrict__ mask, const float* __restrict__ ef,
                              int* __restrict__ slot,
                              float4* __restrict__ records, int E)
{
    int e = blockIdx.x * blockDim.x + threadIdx.x;
    if (e >= E) return;
    int r = rcv[e];
    int t = atomicAdd(&slot[r], 1);
    int s = snd[e];
    float mk = mask[e];
    float4 f = *(const float4*)(ef + 4 * (size_t)e);
    float4 rec;
    rec.x = __int_as_float(s);
    rec.y = mk;
    rec.z = __uint_as_float(pack2h(mk * f.x, mk * f.y));
    rec.w = __uint_as_float(pack2h(mk * f.z, mk * f.w));
    records[(size_t)t] = rec;
}

// ---------------- node-side kernels ----------------

__global__ void init_z_kernel(const float* __restrict__ P,
                              const float* __restrict__ W_in,
                              const float* __restrict__ b_in,
                              const float* __restrict__ Wm,   // [38,32] layer 0
                              const float* __restrict__ bm,
                              float* __restrict__ h,
                              unsigned short* __restrict__ z16,
                              float* __restrict__ V,
                              int N8)
{
    __shared__ float sW[34 * HH];
    __shared__ float sWin[2 * HH];
    __shared__ float sbin[HH];
    __shared__ float sbm[HH];
    for (int i = threadIdx.x; i < 34 * HH; i += blockDim.x) sW[i] = Wm[i];
    if (threadIdx.x < 2 * HH) sWin[threadIdx.x] = W_in[threadIdx.x];
    if (threadIdx.x < HH) { sbin[threadIdx.x] = b_in[threadIdx.x]; sbm[threadIdx.x] = bm[threadIdx.x]; }
    __syncthreads();
    int tid = blockIdx.x * blockDim.x + threadIdx.x;
    if (tid >= N8) return;
    int v = tid >> 3, j = tid & 7;
    float2 p = *(const float2*)(P + 2 * (size_t)v);
    float4 w0 = *(const float4*)&sWin[4 * j];
    float4 w1 = *(const float4*)&sWin[HH + 4 * j];
    float4 b  = *(const float4*)&sbin[4 * j];
    float4 hv;
    hv.x = b.x + p.x * w0.x + p.y * w1.x;
    hv.y = b.y + p.x * w0.y + p.y * w1.y;
    hv.z = b.z + p.x * w0.z + p.y * w1.z;
    hv.w = b.w + p.x * w0.w + p.y * w1.w;
    *(float4*)(h + 4 * (size_t)tid) = hv;
    if (j == 0) { V[2 * v] = 1.0f; V[2 * v + 1] = 0.0f; }
    float4 acc;
    acc.x = sbm[4 * j + 0] + sW[4 * j + 0];
    acc.y = sbm[4 * j + 1] + sW[4 * j + 1];
    acc.z = sbm[4 * j + 2] + sW[4 * j + 2];
    acc.w = sbm[4 * j + 3] + sW[4 * j + 3];
    int base = (threadIdx.x & 63) & ~7;
#pragma unroll
    for (int t = 0; t < 8; t++) {
        float hx = __shfl(hv.x, base + t);
        float hy = __shfl(hv.y, base + t);
        float hz = __shfl(hv.z, base + t);
        float hw = __shfl(hv.w, base + t);
        const float* wr = &sW[(2 + 4 * t) * HH + 4 * j];
        float4 q0 = *(const float4*)(wr);
        float4 q1 = *(const float4*)(wr + HH);
        float4 q2 = *(const float4*)(wr + 2 * HH);
        float4 q3 = *(const float4*)(wr + 3 * HH);
        acc.x += hx * q0.x + hy * q1.x + hz * q2.x + hw * q3.x;
        acc.y += hx * q0.y + hy * q1.y + hz * q2.y + hw * q3.y;
        acc.z += hx * q0.z + hy * q1.z + hz * q2.z + hw * q3.z;
        acc.w += hx * q0.w + hy * q1.w + hz * q2.w + hw * q3.w;
    }
    uint2 q;
    q.x = pack2h(acc.x, acc.y);
    q.y = pack2h(acc.z, acc.w);
    *((uint2*)(z16 + 32 * (size_t)v) + j) = q;
}

// classic pull-gather (fallback paths 0/1; reads padded/CSR records)
__global__ void __launch_bounds__(256)
gather_kernel(const unsigned short* __restrict__ z16,
              const int* __restrict__ row_start,
              const int* __restrict__ cnt,
              int cap,
              const float4* __restrict__ records,
              const float* __restrict__ We,   // [4,32]
              float* __restrict__ h,
              float* __restrict__ pooled,
              int N)
{
    __shared__ float sWe[4 * HH];
    __shared__ float sp[HH];
    if (threadIdx.x < 4 * HH) sWe[threadIdx.x] = We[threadIdx.x];
    if (threadIdx.x < HH) sp[threadIdx.x] = 0.0f;
    __syncthreads();
    int tid = blockIdx.x * blockDim.x + threadIdx.x;
    int v = tid >> 3, j = tid & 7;
    bool active = v < N;
    int k0 = 0, k1 = 0;
    if (active) {
        int len = cnt[v];
        if (cap > 0) {
            if (len > cap) len = cap;
            k0 = cap * v;
        } else {
            k0 = row_start[v];
        }
        k1 = k0 + len;
    }
    const __half2 zero2 = __floats2half2_rn(0.f, 0.f);
    __half2 acc01 = zero2, acc23 = zero2;
    __half2 af01 = zero2, af23 = zero2;
    int base = (threadIdx.x & 63) & ~7;
    const rawf4* recs = (const rawf4*)records;
    rawf4 rn = {0.f, 0.f, 0.f, 0.f};
    if (k0 + j < k1) rn = __builtin_nontemporal_load(&recs[(size_t)(k0 + j)]);
    for (int k = k0; k < k1; k += 8) {
        rawf4 r0 = rn;
        rn.x = 0.f; rn.y = 0.f; rn.z = 0.f; rn.w = 0.f;
        int kn = k + 8 + j;
        if (kn < k1) rn = __builtin_nontemporal_load(&recs[(size_t)kn]);
        int s = __float_as_int(r0.x) & 0xFFFFF;
        int mk2 = (int)h2asu(__float2half2_rn(r0.y));
        af01 = __hadd2(af01, uash2(__float_as_uint(r0.z)));
        af23 = __hadd2(af23, uash2(__float_as_uint(r0.w)));
#pragma unroll
        for (int t = 0; t < 8; t++) {
            int st = __shfl(s, base + t);
            unsigned m2 = (unsigned)__shfl(mk2, base + t);
            uint2 q = *((const uint2*)(z16 + 32 * (size_t)st) + j);
            acc01 = __hfma2(uash2(q.x), uash2(m2), acc01);
            acc23 = __hfma2(uash2(q.y), uash2(m2), acc23);
        }
    }
#pragma unroll
    for (int off = 1; off < 8; off <<= 1) {
        af01 = __hadd2(af01, uash2((unsigned)__shfl_xor((int)h2asu(af01), off)));
        af23 = __hadd2(af23, uash2((unsigned)__shfl_xor((int)h2asu(af23), off)));
    }
    float4 hv = {0.f, 0.f, 0.f, 0.f};
    if (active) {
        float2 a01 = __half22float2(acc01);
        float2 a23 = __half22float2(acc23);
        float2 f01 = __half22float2(af01);
        float2 f23 = __half22float2(af23);
        float4 acc = {a01.x, a01.y, a23.x, a23.y};
        const float* wc = &sWe[4 * j];
        float4 w0 = *(const float4*)(wc);
        float4 w1 = *(const float4*)(wc + HH);
        float4 w2 = *(const float4*)(wc + 2 * HH);
        float4 w3 = *(const float4*)(wc + 3 * HH);
        acc.x += f01.x * w0.x + f01.y * w1.x + f23.x * w2.x + f23.y * w3.x;
        acc.y += f01.x * w0.y + f01.y * w1.y + f23.x * w2.y + f23.y * w3.y;
        acc.z += f01.x * w0.z + f01.y * w1.z + f23.x * w2.z + f23.y * w3.z;
        acc.w += f01.x * w0.w + f01.y * w1.w + f23.x * w2.w + f23.y * w3.w;
        hv.x = fmaxf(acc.x, 0.f);
        hv.y = fmaxf(acc.y, 0.f);
        hv.z = fmaxf(acc.z, 0.f);
        hv.w = fmaxf(acc.w, 0.f);
        *(float4*)(h + 4 * (size_t)tid) = hv;
    }
#pragma unroll
    for (int off = 8; off < 64; off <<= 1) {
        hv.x += __shfl_xor(hv.x, off);
        hv.y += __shfl_xor(hv.y, off);
        hv.z += __shfl_xor(hv.z, off);
        hv.w += __shfl_xor(hv.w, off);
    }
    if ((threadIdx.x & 63) < 8) {
        atomicAdd(&sp[4 * j + 0], hv.x);
        atomicAdd(&sp[4 * j + 1], hv.y);
        atomicAdd(&sp[4 * j + 2], hv.z);
        atomicAdd(&sp[4 * j + 3], hv.w);
    }
    __syncthreads();
    if (threadIdx.x < HH) unsafeAtomicAdd(&pooled[threadIdx.x], sp[threadIdx.x]);
}

// fused: g update + node update + next-layer z16
__global__ void update_kernel(const float* __restrict__ h,
                              const float* __restrict__ g_in,
                              float* __restrict__ g_out,
                              const float* __restrict__ pooled,
                              float invN,
                              const float* __restrict__ Wg,
                              const float* __restrict__ bg,
                              const float* __restrict__ Wn,
                              const float* __restrict__ bn,
                              const float* __restrict__ Wout,
                              const float* __restrict__ bout,
                              float* __restrict__ V,
                              const float* __restrict__ Wm,
                              const float* __restrict__ bm,
                              unsigned short* __restrict__ z16,
                              int has_next,
                              int N8)
{
    __shared__ float sWn[64 * HH];
    __shared__ float sWm[34 * HH];
    __shared__ float sgnew[HH];
    __shared__ float sgp[64];
    __shared__ float sWo[HH * 2];
    __shared__ float sb[2 * HH + 2];
    for (int i = threadIdx.x; i < 64 * HH; i += blockDim.x) sWn[i] = Wn[i];
    if (has_next)
        for (int i = threadIdx.x; i < 34 * HH; i += blockDim.x) sWm[i] = Wm[i];
    if (threadIdx.x < 64)
        sgp[threadIdx.x] = (threadIdx.x < HH) ? g_in[threadIdx.x]
                                              : pooled[threadIdx.x - HH] * invN;
    if (threadIdx.x < HH * 2) sWo[threadIdx.x] = Wout[threadIdx.x];
    if (threadIdx.x < HH) sb[threadIdx.x] = bn[threadIdx.x];
    if (threadIdx.x < 2) sb[2 * HH + threadIdx.x] = bout[threadIdx.x];
    if (has_next && threadIdx.x >= 64 && threadIdx.x < 64 + HH)
        sb[HH + threadIdx.x - 64] = bm[threadIdx.x - 64];
    __syncthreads();
    if (threadIdx.x < HH) {
        int k = threadIdx.x;
        float acc = bg[k];
#pragma unroll 8
        for (int i = 0; i < 64; i++) acc += sgp[i] * Wg[i * HH + k];
        sgnew[k] = fmaxf(acc, 0.f);
    }
    __syncthreads();
    if (blockIdx.x == 0 && threadIdx.x < HH) g_out[threadIdx.x] = sgnew[threadIdx.x];

    int tid = blockIdx.x * blockDim.x + threadIdx.x;
    if (tid >= N8) return;
    int v = tid >> 3, j = tid & 7;
    float4 hv = *(const float4*)(h + 4 * (size_t)tid);
    float4 acc;
    acc.x = sb[4 * j + 0]; acc.y = sb[4 * j + 1];
    acc.z = sb[4 * j + 2]; acc.w = sb[4 * j + 3];
#pragma unroll 8
    for (int i = 0; i < HH; i++) {
        float gi = sgnew[i];
        const float4 w = *(const float4*)&sWn[(HH + i) * HH + 4 * j];
        acc.x += gi * w.x; acc.y += gi * w.y;
        acc.z += gi * w.z; acc.w += gi * w.w;
    }
    int base = (threadIdx.x & 63) & ~7;
#pragma unroll
    for (int t = 0; t < 8; t++) {
        float hx = __shfl(hv.x, base + t);
        float hy = __shfl(hv.y, base + t);
        float hz = __shfl(hv.z, base + t);
        float hw = __shfl(hv.w, base + t);
        const float* wr = &sWn[(4 * t) * HH + 4 * j];
        float4 q0 = *(const float4*)(wr);
        float4 q1 = *(const float4*)(wr + HH);
        float4 q2 = *(const float4*)(wr + 2 * HH);
        float4 q3 = *(const float4*)(wr + 3 * HH);
        acc.x += hx * q0.x + hy * q1.x + hz * q2.x + hw * q3.x;
        acc.y += hx * q0.y + hy * q1.y + hz * q2.y + hw * q3.y;
        acc.z += hx * q0.z + hy * q1.z + hz * q2.z + hw * q3.z;
        acc.w += hx * q0.w + hy * q1.w + hz * q2.w + hw * q3.w;
    }
    float4 hn;
    hn.x = fmaxf(acc.x, 0.f);
    hn.y = fmaxf(acc.y, 0.f);
    hn.z = fmaxf(acc.z, 0.f);
    hn.w = fmaxf(acc.w, 0.f);
    float p0 = hn.x * sWo[(4 * j + 0) * 2 + 0] + hn.y * sWo[(4 * j + 1) * 2 + 0]
             + hn.z * sWo[(4 * j + 2) * 2 + 0] + hn.w * sWo[(4 * j + 3) * 2 + 0];
    float p1 = hn.x * sWo[(4 * j + 0) * 2 + 1] + hn.y * sWo[(4 * j + 1) * 2 + 1]
             + hn.z * sWo[(4 * j + 2) * 2 + 1] + hn.w * sWo[(4 * j + 3) * 2 + 1];
#pragma unroll
    for (int off = 1; off < 8; off <<= 1) {
        p0 += __shfl_xor(p0, off);
        p1 += __shfl_xor(p1, off);
    }
    float2 Vold = *(const float2*)(V + 2 * v);
    float2 Vnew;
    Vnew.x = Vold.x + p0 + sb[2 * HH + 0];
    Vnew.y = Vold.y + p1 + sb[2 * HH + 1];
    if (j == 0) *(float2*)(V + 2 * v) = Vnew;
    if (!has_next) return;
    float4 az;
    az.x = sb[HH + 4 * j + 0] + Vnew.x * sWm[4 * j + 0] + Vnew.y * sWm[HH + 4 * j + 0];
    az.y = sb[HH + 4 * j + 1] + Vnew.x * sWm[4 * j + 1] + Vnew.y * sWm[HH + 4 * j + 1];
    az.z = sb[HH + 4 * j + 2] + Vnew.x * sWm[4 * j + 2] + Vnew.y * sWm[HH + 4 * j + 2];
    az.w = sb[HH + 4 * j + 3] + Vnew.x * sWm[4 * j + 3] + Vnew.y * sWm[HH + 4 * j + 3];
#pragma unroll
    for (int t = 0; t < 8; t++) {
        float hx = __shfl(hn.x, base + t);
        float hy = __shfl(hn.y, base + t);
        float hz = __shfl(hn.z, base + t);
        float hw = __shfl(hn.w, base + t);
        const float* wr = &sWm[(2 + 4 * t) * HH + 4 * j];
        float4 q0 = *(const float4*)(wr);
        float4 q1 = *(const float4*)(wr + HH);
        float4 q2 = *(const float4*)(wr + 2 * HH);
        float4 q3 = *(const float4*)(wr + 3 * HH);
        az.x += hx * q0.x + hy * q1.x + hz * q2.x + hw * q3.x;
        az.y += hx * q0.y + hy * q1.y + hz * q2.y + hw * q3.y;
        az.z += hx * q0.z + hy * q1.z + hz * q2.z + hw * q3.z;
        az.w += hx * q0.w + hy * q1.w + hz * q2.w + hw * q3.w;
    }
    uint2 q;
    q.x = pack2h(az.x, az.y);
    q.y = pack2h(az.z, az.w);
    *((uint2*)(z16 + 32 * (size_t)v) + j) = q;
}

extern "C" void kernel_launch(void* const* d_in, const int* in_sizes, int n_in,
                              void* d_out, int out_size, void* d_ws, size_t ws_size,
                              hipStream_t stream)
{
    const float* P     = (const float*)d_in[0];
    const int*   snd   = (const int*)d_in[1];
    const int*   rcv   = (const int*)d_in[2];
    const float* ef    = (const float*)d_in[3];
    const float* mask  = (const float*)d_in[4];
    const float* W_in  = (const float*)d_in[5];
    const float* b_in  = (const float*)d_in[6];
    const float* W_msg = (const float*)d_in[7];
    const float* b_msg = (const float*)d_in[8];
    const float* W_g   = (const float*)d_in[9];
    const float* b_g   = (const float*)d_in[10];
    const float* W_n   = (const float*)d_in[11];
    const float* b_n   = (const float*)d_in[12];
    const float* W_out = (const float*)d_in[13];
    const float* b_out = (const float*)d_in[14];
    float* V = (float*)d_out;

    const int N = in_sizes[0] / 2;
    const int E = in_sizes[1];
    const int N8 = N * 8;
    const int NB = (N + 255) / 256;
    const int nbuck = (N + (1 << BSH) - 1) >> BSH;   // <= 1024 for N<=131072

    dim3 blk(256);
    int gn = (N8 + 255) / 256;
    int ge = (E + 255) / 256;
    int g1 = (E + P1_EPB - 1) / P1_EPB;

    // path-2 eligibility: partition capacity fits the compile-time LDS cap
    long long bexp = ((long long)E << BSH) / (N > 0 ? N : 1);
    int need = (int)((double)bexp + 10.0 * sqrt((double)bexp) + 64.0);
    size_t p2bytes = (size_t)nbuck * P2CAP * 16          // bA + bB
                   + 128ull * (size_t)N                  // h
                   + 64ull * (size_t)N                   // z16
                   + 8ull * (size_t)N                    // F16
                   + 4ull * (MAXB + 7 * HH) + 4096;
    bool p2ok = (need <= P2CAP) && (nbuck <= MAXB) && (N < (1 << 20)) &&
                (ws_size >= p2bytes);

    if (p2ok) {
        uint2* bA = (uint2*)d_ws;
        uint2* bB = bA + (size_t)nbuck * P2CAP;
        float* h = (float*)(bB + (size_t)nbuck * P2CAP);
        unsigned short* z16 = (unsigned short*)(h + (size_t)N * HH);
        uint2* F16 = (uint2*)(z16 + (size_t)N * HH);
        int* tail = (int*)(F16 + N);
        float* pooled = (float*)(tail + MAXB);
        float* g_buf = pooled + 3 * HH;
        (void)hipMemsetAsync(tail, 0, (MAXB + 7 * HH) * sizeof(int), stream);
        pass1_bin_kernel<<<g1, dim3(P1_TPB), 0, stream>>>(snd, rcv, mask, ef, tail,
                                                          bA, bB, E, nbuck, P2CAP);
        init_z_kernel<<<gn, blk, 0, stream>>>(P, W_in, b_in, W_msg, b_msg, h, z16, V, N8);
        for (int l = 0; l < 3; l++) {
            const float* Wm = W_msg + (size_t)l * 38 * HH;
            const float* Wm_next = W_msg + (size_t)(l + 1) * 38 * HH;
            if (l == 0)
                gather_part_kernel<1><<<nbuck, dim3(1024), 0, stream>>>(
                    z16, tail, bA, bB, Wm + 34 * HH, h, F16, pooled + l * HH, N);
            else
                gather_part_kernel<0><<<nbuck, dim3(1024), 0, stream>>>(
                    z16, tail, bA, bB, Wm + 34 * HH, h, F16, pooled + l * HH, N);
            update_kernel<<<gn, blk, 0, stream>>>(h, g_buf + l * HH, g_buf + (l + 1) * HH,
                                                  pooled + l * HH, 1.0f / (float)N,
                                                  W_g + (size_t)l * 64 * HH, b_g + l * HH,
                                                  W_n + (size_t)l * 64 * HH, b_n + l * HH,
                                                  W_out + (size_t)l * HH * 2, b_out + l * 2,
                                                  V,
                                                  (l < 2) ? Wm_next : Wm,
                                                  (l < 2) ? (b_msg + (l + 1) * HH) : (b_msg + l * HH),
                                                  z16, (l < 2) ? 1 : 0, N8);
        }
        return;
    }

    // ---------------- fallback paths (padded / exact CSR) ----------------
    size_t fixed = 128 * (size_t)N + 64 * (size_t)N + 4 * (size_t)N
                 + 4 * (MAXB + 7 * HH) + 4096;
    size_t avail = (ws_size > fixed) ? ws_size - fixed : 0;
    int path, cap = 0;
    {
        long cap1 = (long)(avail / (16 * (size_t)N));
        if (cap1 >= 72) { path = 1; cap = (cap1 > 96) ? 96 : (int)cap1; }
        else             path = 0;
    }

    if (path == 1) {
        float4* records = (float4*)d_ws;
        float*  h       = (float*)(records + (size_t)cap * N);
        unsigned short* z16 = (unsigned short*)(h + (size_t)N * HH);
        int* cnt        = (int*)(z16 + (size_t)N * HH);
        float* pooled   = (float*)(cnt + N);
        float* g_buf    = pooled + 3 * HH;
        (void)hipMemsetAsync(cnt, 0, ((size_t)N + 7 * HH) * sizeof(int), stream);
        build1_kernel<<<ge, blk, 0, stream>>>(snd, rcv, mask, ef, cnt, cap, records, E);
        init_z_kernel<<<gn, blk, 0, stream>>>(P, W_in, b_in, W_msg, b_msg, h, z16, V, N8);
        for (int l = 0; l < 3; l++) {
            const float* Wm = W_msg + (size_t)l * 38 * HH;
            const float* Wm_next = W_msg + (size_t)(l + 1) * 38 * HH;
            gather_kernel<<<gn, blk, 0, stream>>>(z16, cnt, cnt, cap, records,
                                                  Wm + 34 * HH, h, pooled + l * HH, N);
            update_kernel<<<gn, blk, 0, stream>>>(h, g_buf + l * HH, g_buf + (l + 1) * HH,
                                                  pooled + l * HH, 1.0f / (float)N,
                                                  W_g + (size_t)l * 64 * HH, b_g + l * HH,
                                                  W_n + (size_t)l * 64 * HH, b_n + l * HH,
                                                  W_out + (size_t)l * HH * 2, b_out + l * 2,
                                                  V,
                                                  (l < 2) ? Wm_next : Wm,
                                                  (l < 2) ? (b_msg + (l + 1) * HH) : (b_msg + l * HH),
                                                  z16, (l < 2) ? 1 : 0, N8);
        }
    } else {
        float4* records  = (float4*)d_ws;
        float*  h        = (float*)(records + (size_t)E);
        unsigned short* z16 = (unsigned short*)(h + (size_t)N * HH);
        int* cnt         = (int*)(z16 + (size_t)N * HH);
        int* row_start   = cnt + N;
        int* off         = row_start + (N + 1);
        int* bsum        = off + N;
        int* boff        = bsum + 512;
        float* pooled    = (float*)(boff + 512);
        float* g_buf     = pooled + 3 * HH;
        (void)hipMemsetAsync(cnt, 0, ((size_t)(3 * N + 1 + 1024) + 7 * HH) * sizeof(int), stream);
        hist_kernel<<<ge, blk, 0, stream>>>(rcv, cnt, E);
        block_sum_kernel<<<NB, blk, 0, stream>>>(cnt, bsum, N);
        scan_bsum_kernel<<<1, 512, 0, stream>>>(bsum, boff, NB);
        local_scan_kernel<<<NB, blk, 0, stream>>>(cnt, boff, row_start, off, N);
        build0_kernel<<<ge, blk, 0, stream>>>(snd, rcv, mask, ef, off, records, E);
        init_z_kernel<<<gn, blk, 0, stream>>>(P, W_in, b_in, W_msg, b_msg, h, z16, V, N8);
        for (int l = 0; l < 3; l++) {
            const float* Wm = W_msg + (size_t)l * 38 * HH;
            const float* Wm_next = W_msg + (size_t)(l + 1) * 38 * HH;
            gather_kernel<<<gn, blk, 0, stream>>>(z16, row_start, cnt, 0, records,
                                                  Wm + 34 * HH, h, pooled + l * HH, N);
            update_kernel<<<gn, blk, 0, stream>>>(h, g_buf + l * HH, g_buf + (l + 1) * HH,
                                                  pooled + l * HH, 1.0f / (float)N,
                                                  W_g + (size_t)l * 64 * HH, b_g + l * HH,
                                                  W_n + (size_t)l * 64 * HH, b_n + l * HH,
                                                  W_out + (size_t)l * HH * 2, b_out + l * 2,
                                                  V,
                                                  (l < 2) ? Wm_next : Wm,
                                                  (l < 2) ? (b_msg + (l + 1) * HH) : (b_msg + l * HH),
                                                  z16, (l < 2) ? 1 : 0, N8);
        }
    }
}

// Round 10
// 424.603 us; speedup vs baseline: 1.2602x; 1.0398x over previous
//
#include <hip/hip_runtime.h>
#include <hip/hip_fp16.h>
#include <math.h>

// GNN power-flow forward. N=100k, E=3.2M, H=32, L=3, FE=4.
// R20: R15 base (proven 441us, re-verified R19) + gather-internal LDS
// compaction ONLY. The R17/R18 3-plane layout failed twice (cause unproven:
// infra vs delta); this captures its main lever (L0 occupancy) with zero
// changes to pass1 / workspace layout / launcher:
//  - gather phase A3 stores grouped {sender 4B (aS), f16 mask 2B (aM)}
//    instead of the 8B uint2 aG. Numerically identical (mask was already
//    consumed as f16 in phase B).
//  - L0 LDS 82.4 -> 72.0KB => 2 blocks/CU (occupancy 31 -> ~62%).
//  - L1/2 LDS 42 -> 32KB (thread-capped at 2 blk/CU, unchanged).

#define HH 32        // hidden dim
#define BSH 7        // bucket shift: 128 receivers per partition
#define MAXB 1024    // max partitions (N <= 131072)
#define P2CAP 4992   // fixed per-partition record capacity (path 2)
#define P1_TPB 1024  // pass1 threads per block
#define P1_EPT 8     // pass1 edges per thread
#define P1_EPB (P1_TPB * P1_EPT)   // 8192 edges per block

typedef float rawf4 __attribute__((ext_vector_type(4)));

__device__ __forceinline__ unsigned pack2h(float a, float b) {
    return ((unsigned)__half_as_ushort(__float2half_rn(b)) << 16) |
           (unsigned)__half_as_ushort(__float2half_rn(a));
}
__device__ __forceinline__ __half2 uash2(unsigned u) {
    return *reinterpret_cast<__half2*>(&u);
}
__device__ __forceinline__ unsigned h2asu(__half2 h) {
    return *reinterpret_cast<unsigned*>(&h);
}

// ---------------- build (path 2) ----------------

// pass 1: block-local LDS binning. 8192 edges/block -> LDS hist over
// partitions -> LDS scan -> one global reservation per partition ->
// scatter records into LDS -> coalesced SoA copy-out (A + B arrays).
__global__ void __launch_bounds__(P1_TPB)
pass1_bin_kernel(const int* __restrict__ snd, const int* __restrict__ rcv,
                 const float* __restrict__ mask, const float* __restrict__ ef,
                 int* __restrict__ tail,
                 uint2* __restrict__ bA, uint2* __restrict__ bB,
                 int E, int nbuck, int bcap)
{
    __shared__ float4 srec[P1_EPB];            // 128KB
    __shared__ unsigned short sbid[P1_EPB];    // 16KB
    __shared__ int cur[MAXB];
    __shared__ int dlt[MAXB];
    int lo = blockIdx.x * P1_EPB;
    int n = E - lo; if (n > P1_EPB) n = P1_EPB;
    int t = threadIdx.x;

    for (int i = t; i < MAXB; i += P1_TPB) cur[i] = 0;
    __syncthreads();

    int rv[P1_EPT];
#pragma unroll
    for (int i = 0; i < P1_EPT; i++) {
        int e = lo + t + i * P1_TPB;
        int r = (e < E) ? rcv[e] : -1;
        rv[i] = r;
        if (r >= 0) atomicAdd(&cur[r >> BSH], 1);
    }
    __syncthreads();

    int v = (t < nbuck) ? cur[t] : 0;
    dlt[t] = v;
    __syncthreads();
    for (int off = 1; off < P1_TPB; off <<= 1) {
        int x = (t >= off) ? dlt[t - off] : 0;
        __syncthreads();
        dlt[t] += x;
        __syncthreads();
    }
    int lstart = dlt[t] - v;
    int gbase = 0;
    if (t < nbuck && v > 0) gbase = atomicAdd(&tail[t], v);
    __syncthreads();
    cur[t] = lstart;
    dlt[t] = gbase - lstart;
    __syncthreads();

#pragma unroll
    for (int i = 0; i < P1_EPT; i++) {
        int r = rv[i];
        if (r < 0) continue;
        int e = lo + t + i * P1_TPB;
        int b = r >> BSH;
        int pos = atomicAdd(&cur[b], 1);
        int s = snd[e];
        float mk = mask[e];
        float4 f = *(const float4*)(ef + 4 * (size_t)e);
        float4 rec;
        rec.x = __int_as_float(s | ((r & ((1 << BSH) - 1)) << 20));
        rec.y = mk;
        rec.z = __uint_as_float(pack2h(mk * f.x, mk * f.y));
        rec.w = __uint_as_float(pack2h(mk * f.z, mk * f.w));
        srec[pos] = rec;
        sbid[pos] = (unsigned short)b;
    }
    __syncthreads();

    for (int i = t; i < n; i += P1_TPB) {
        int b = sbid[i];
        unsigned oin = (unsigned)(i + dlt[b]);
        if (oin < (unsigned)bcap) {
            float4 rec = srec[i];
            size_t o = (size_t)b * bcap + oin;
            uint2 a; a.x = __float_as_uint(rec.x); a.y = __float_as_uint(rec.y);
            bA[o] = a;
            uint2 bb; bb.x = __float_as_uint(rec.z); bb.y = __float_as_uint(rec.w);
            bB[o] = bb;
        }
    }
}

// fused group+gather: one block per 128-receiver partition.
// Phase A: LDS hist (lo-word read) -> scan -> scatter compact {aS, aM}(+bG)
// grouped by rloc (mask converted to f16 here; consumed as f16 anyway).
// Phase B: 128 groups x 8 lanes run the classic z16-gather loop from LDS.
// L0==1: also accumulate af from B and write F16[v]. L0==0: read F16[v].
template<int L0>
__global__ void __launch_bounds__(1024)
gather_part_kernel(const unsigned short* __restrict__ z16,
                   const int* __restrict__ tail,
                   const uint2* __restrict__ bA,
                   const uint2* __restrict__ bB,
                   const float* __restrict__ We,   // [4,32] this layer
                   float* __restrict__ h,
                   uint2* __restrict__ F16,
                   float* __restrict__ pooled,
                   int N)
{
    __shared__ unsigned aS[P2CAP];          // sender (20b)
    __shared__ unsigned short aM[P2CAP];    // f16 mask
    __shared__ uint2 bG[L0 ? P2CAP : 1];
    __shared__ int hist[1 << BSH];
    __shared__ int bse[1 << BSH];
    __shared__ int cur[1 << BSH];
    __shared__ float sWe[4 * HH];
    __shared__ float sp[HH];
    int t = threadIdx.x, b = blockIdx.x;
    if (t < (1 << BSH)) hist[t] = 0;
    if (t < 4 * HH) sWe[t] = We[t];
    if (t < HH) sp[t] = 0.0f;
    __syncthreads();
    int n = tail[b];
    if (n > P2CAP) n = P2CAP;
    if (n < 0) n = 0;
    size_t gb = (size_t)b * P2CAP;

    // A1: histogram by rloc (read lo word only; segment stays L2-hot)
    const unsigned* loA = (const unsigned*)(bA + gb);
    for (int i = t; i < n; i += 1024)
        atomicAdd(&hist[(loA[2 * i] >> 20) & ((1 << BSH) - 1)], 1);
    __syncthreads();

    // A2: exclusive scan over 128 rlocs
    if (t < (1 << BSH)) bse[t] = hist[t];
    __syncthreads();
    for (int off = 1; off < (1 << BSH); off <<= 1) {
        int x = (t < (1 << BSH) && t >= off) ? bse[t - off] : 0;
        __syncthreads();
        if (t < (1 << BSH)) bse[t] += x;
        __syncthreads();
    }
    if (t < (1 << BSH)) { int s0 = bse[t] - hist[t]; bse[t] = s0; cur[t] = s0; }
    __syncthreads();

    // A3: scatter into grouped compact LDS lists (re-read is L2-hot)
    for (int i = t; i < n; i += 1024) {
        uint2 a = bA[gb + i];
        int rl = (a.x >> 20) & ((1 << BSH) - 1);
        int p = atomicAdd(&cur[rl], 1);
        aS[p] = a.x & 0xFFFFF;
        aM[p] = __half_as_ushort(__float2half_rn(__uint_as_float(a.y)));
        if (L0) bG[p] = bB[gb + i];
    }
    __syncthreads();

    // B: per-receiver gather. group g handles receiver (b<<7)+g.
    int g = t >> 3, j = t & 7;
    int r = (b << BSH) + g;
    bool active = r < N;
    int k0 = bse[g], k1 = cur[g];
    const __half2 zero2 = __floats2half2_rn(0.f, 0.f);
    __half2 acc01 = zero2, acc23 = zero2, af01 = zero2, af23 = zero2;
    int lanebase = (t & 63) & ~7;
    for (int k = k0; k < k1; k += 8) {
        int idx = k + j;
        int s = 0, mk2 = 0;
        if (idx < k1) {
            s = (int)aS[idx];
            unsigned mv = (unsigned)aM[idx];
            mk2 = (int)(mv | (mv << 16));
            if (L0) {
                uint2 bb = bG[idx];
                af01 = __hadd2(af01, uash2(bb.x));
                af23 = __hadd2(af23, uash2(bb.y));
            }
        }
#pragma unroll
        for (int q8 = 0; q8 < 8; q8++) {
            int st = __shfl(s, lanebase + q8);
            unsigned m2 = (unsigned)__shfl(mk2, lanebase + q8);
            uint2 qv = *((const uint2*)(z16 + 32 * (size_t)st) + j);
            acc01 = __hfma2(uash2(qv.x), uash2(m2), acc01);
            acc23 = __hfma2(uash2(qv.y), uash2(m2), acc23);
        }
    }
    if (L0) {
#pragma unroll
        for (int off = 1; off < 8; off <<= 1) {
            af01 = __hadd2(af01, uash2((unsigned)__shfl_xor((int)h2asu(af01), off)));
            af23 = __hadd2(af23, uash2((unsigned)__shfl_xor((int)h2asu(af23), off)));
        }
        if (active && j == 0) {
            uint2 f; f.x = h2asu(af01); f.y = h2asu(af23);
            F16[r] = f;
        }
    } else {
        if (active) {
            uint2 f = F16[r];
            af01 = uash2(f.x);
            af23 = uash2(f.y);
        }
    }
    float4 hv = {0.f, 0.f, 0.f, 0.f};
    if (active) {
        float2 a01 = __half22float2(acc01);
        float2 a23 = __half22float2(acc23);
        float2 f01 = __half22float2(af01);
        float2 f23 = __half22float2(af23);
        float4 acc = {a01.x, a01.y, a23.x, a23.y};
        const float* wc = &sWe[4 * j];
        float4 w0 = *(const float4*)(wc);
        float4 w1 = *(const float4*)(wc + HH);
        float4 w2 = *(const float4*)(wc + 2 * HH);
        float4 w3 = *(const float4*)(wc + 3 * HH);
        acc.x += f01.x * w0.x + f01.y * w1.x + f23.x * w2.x + f23.y * w3.x;
        acc.y += f01.x * w0.y + f01.y * w1.y + f23.x * w2.y + f23.y * w3.y;
        acc.z += f01.x * w0.z + f01.y * w1.z + f23.x * w2.z + f23.y * w3.z;
        acc.w += f01.x * w0.w + f01.y * w1.w + f23.x * w2.w + f23.y * w3.w;
        hv.x = fmaxf(acc.x, 0.f);
        hv.y = fmaxf(acc.y, 0.f);
        hv.z = fmaxf(acc.z, 0.f);
        hv.w = fmaxf(acc.w, 0.f);
        rawf4 hvr;
        hvr.x = hv.x; hvr.y = hv.y; hvr.z = hv.z; hvr.w = hv.w;
        __builtin_nontemporal_store(hvr, (rawf4*)(h + 32 * (size_t)r + 4 * j));
    }
#pragma unroll
    for (int off = 8; off < 64; off <<= 1) {
        hv.x += __shfl_xor(hv.x, off);
        hv.y += __shfl_xor(hv.y, off);
        hv.z += __shfl_xor(hv.z, off);
        hv.w += __shfl_xor(hv.w, off);
    }
    if ((t & 63) < 8) {
        atomicAdd(&sp[4 * j + 0], hv.x);
        atomicAdd(&sp[4 * j + 1], hv.y);
        atomicAdd(&sp[4 * j + 2], hv.z);
        atomicAdd(&sp[4 * j + 3], hv.w);
    }
    __syncthreads();
    if (t < HH) unsafeAtomicAdd(&pooled[t], sp[t]);
}

// ---------------- single-pass padded build (path 1 fallback) ----------------

__global__ void build1_kernel(const int* __restrict__ snd, const int* __restrict__ rcv,
                              const float* __restrict__ mask, const float* __restrict__ ef,
                              int* __restrict__ slot, int cap,
                              float4* __restrict__ records, int E)
{
    int e = blockIdx.x * blockDim.x + threadIdx.x;
    if (e >= E) return;
    int r = rcv[e];
    int t = atomicAdd(&slot[r], 1);
    if (t >= cap) return;
    size_t pos = (size_t)cap * r + t;
    int s = snd[e];
    float mk = mask[e];
    float4 f = *(const float4*)(ef + 4 * (size_t)e);
    float4 rec;
    rec.x = __int_as_float(s);
    rec.y = mk;
    rec.z = __uint_as_float(pack2h(mk * f.x, mk * f.y));
    rec.w = __uint_as_float(pack2h(mk * f.z, mk * f.w));
    records[pos] = rec;
}

// ---------------- exact-CSR fallback (path 0) ----------------

__global__ void hist_kernel(const int* __restrict__ rcv, int* __restrict__ deg, int E)
{
    int e = blockIdx.x * blockDim.x + threadIdx.x;
    if (e < E) atomicAdd(&deg[rcv[e]], 1);
}

__global__ void block_sum_kernel(const int* __restrict__ deg, int* __restrict__ bsum, int N)
{
    __shared__ int s[256];
    int i = blockIdx.x * 256 + threadIdx.x;
    s[threadIdx.x] = (i < N) ? deg[i] : 0;
    __syncthreads();
    for (int off = 128; off > 0; off >>= 1) {
        if (threadIdx.x < off) s[threadIdx.x] += s[threadIdx.x + off];
        __syncthreads();
    }
    if (threadIdx.x == 0) bsum[blockIdx.x] = s[0];
}

__global__ void scan_bsum_kernel(const int* __restrict__ bsum, int* __restrict__ boff, int NB)
{
    __shared__ int s[512];
    int t = threadIdx.x;
    int v = (t < NB) ? bsum[t] : 0;
    s[t] = v;
    __syncthreads();
    for (int off = 1; off < 512; off <<= 1) {
        int x = (t >= off) ? s[t - off] : 0;
        __syncthreads();
        s[t] += x;
        __syncthreads();
    }
    if (t < NB) boff[t] = s[t] - v;
}

__global__ void local_scan_kernel(const int* __restrict__ deg, const int* __restrict__ boff,
                                  int* __restrict__ row_start, int* __restrict__ off, int N)
{
    __shared__ int s[256];
    int i = blockIdx.x * 256 + threadIdx.x;
    int v = (i < N) ? deg[i] : 0;
    s[threadIdx.x] = v;
    __syncthreads();
    for (int o = 1; o < 256; o <<= 1) {
        int x = (threadIdx.x >= o) ? s[threadIdx.x - o] : 0;
        __syncthreads();
        s[threadIdx.x] += x;
        __syncthreads();
    }
    if (i < N) {
        int r = boff[blockIdx.x] + s[threadIdx.x] - v;
        row_start[i] = r;
        off[i] = r;
    }
}

__global__ void build0_kernel(const int* __restrict__ snd, const int* __restrict__ rcv,
                              const float* __restrict__ mask, const float* __restrict__ ef,
                              int* __restrict__ slot,
                              float4* __restrict__ records, int E)
{
    int e = blockIdx.x * blockDim.x + threadIdx.x;
    if (e >= E) return;
    int r = rcv[e];
    int t = atomicAdd(&slot[r], 1);
    int s = snd[e];
    float mk = mask[e];
    float4 f = *(const float4*)(ef + 4 * (size_t)e);
    float4 rec;
    rec.x = __int_as_float(s);
    rec.y = mk;
    rec.z = __uint_as_float(pack2h(mk * f.x, mk * f.y));
    rec.w = __uint_as_float(pack2h(mk * f.z, mk * f.w));
    records[(size_t)t] = rec;
}

// ---------------- node-side kernels ----------------

__global__ void init_z_kernel(const float* __restrict__ P,
                              const float* __restrict__ W_in,
                              const float* __restrict__ b_in,
                              const float* __restrict__ Wm,   // [38,32] layer 0
                              const float* __restrict__ bm,
                              float* __restrict__ h,
                              unsigned short* __restrict__ z16,
                              float* __restrict__ V,
                              int N8)
{
    __shared__ float sW[34 * HH];
    __shared__ float sWin[2 * HH];
    __shared__ float sbin[HH];
    __shared__ float sbm[HH];
    for (int i = threadIdx.x; i < 34 * HH; i += blockDim.x) sW[i] = Wm[i];
    if (threadIdx.x < 2 * HH) sWin[threadIdx.x] = W_in[threadIdx.x];
    if (threadIdx.x < HH) { sbin[threadIdx.x] = b_in[threadIdx.x]; sbm[threadIdx.x] = bm[threadIdx.x]; }
    __syncthreads();
    int tid = blockIdx.x * blockDim.x + threadIdx.x;
    if (tid >= N8) return;
    int v = tid >> 3, j = tid & 7;
    float2 p = *(const float2*)(P + 2 * (size_t)v);
    float4 w0 = *(const float4*)&sWin[4 * j];
    float4 w1 = *(const float4*)&sWin[HH + 4 * j];
    float4 b  = *(const float4*)&sbin[4 * j];
    float4 hv;
    hv.x = b.x + p.x * w0.x + p.y * w1.x;
    hv.y = b.y + p.x * w0.y + p.y * w1.y;
    hv.z = b.z + p.x * w0.z + p.y * w1.z;
    hv.w = b.w + p.x * w0.w + p.y * w1.w;
    *(float4*)(h + 4 * (size_t)tid) = hv;
    if (j == 0) { V[2 * v] = 1.0f; V[2 * v + 1] = 0.0f; }
    float4 acc;
    acc.x = sbm[4 * j + 0] + sW[4 * j + 0];
    acc.y = sbm[4 * j + 1] + sW[4 * j + 1];
    acc.z = sbm[4 * j + 2] + sW[4 * j + 2];
    acc.w = sbm[4 * j + 3] + sW[4 * j + 3];
    int base = (threadIdx.x & 63) & ~7;
#pragma unroll
    for (int t = 0; t < 8; t++) {
        float hx = __shfl(hv.x, base + t);
        float hy = __shfl(hv.y, base + t);
        float hz = __shfl(hv.z, base + t);
        float hw = __shfl(hv.w, base + t);
        const float* wr = &sW[(2 + 4 * t) * HH + 4 * j];
        float4 q0 = *(const float4*)(wr);
        float4 q1 = *(const float4*)(wr + HH);
        float4 q2 = *(const float4*)(wr + 2 * HH);
        float4 q3 = *(const float4*)(wr + 3 * HH);
        acc.x += hx * q0.x + hy * q1.x + hz * q2.x + hw * q3.x;
        acc.y += hx * q0.y + hy * q1.y + hz * q2.y + hw * q3.y;
        acc.z += hx * q0.z + hy * q1.z + hz * q2.z + hw * q3.z;
        acc.w += hx * q0.w + hy * q1.w + hz * q2.w + hw * q3.w;
    }
    uint2 q;
    q.x = pack2h(acc.x, acc.y);
    q.y = pack2h(acc.z, acc.w);
    *((uint2*)(z16 + 32 * (size_t)v) + j) = q;
}

// classic pull-gather (fallback paths 0/1; reads padded/CSR records)
__global__ void __launch_bounds__(256)
gather_kernel(const unsigned short* __restrict__ z16,
              const int* __restrict__ row_start,
              const int* __restrict__ cnt,
              int cap,
              const float4* __restrict__ records,
              const float* __restrict__ We,   // [4,32]
              float* __restrict__ h,
              float* __restrict__ pooled,
              int N)
{
    __shared__ float sWe[4 * HH];
    __shared__ float sp[HH];
    if (threadIdx.x < 4 * HH) sWe[threadIdx.x] = We[threadIdx.x];
    if (threadIdx.x < HH) sp[threadIdx.x] = 0.0f;
    __syncthreads();
    int tid = blockIdx.x * blockDim.x + threadIdx.x;
    int v = tid >> 3, j = tid & 7;
    bool active = v < N;
    int k0 = 0, k1 = 0;
    if (active) {
        int len = cnt[v];
        if (cap > 0) {
            if (len > cap) len = cap;
            k0 = cap * v;
        } else {
            k0 = row_start[v];
        }
        k1 = k0 + len;
    }
    const __half2 zero2 = __floats2half2_rn(0.f, 0.f);
    __half2 acc01 = zero2, acc23 = zero2;
    __half2 af01 = zero2, af23 = zero2;
    int base = (threadIdx.x & 63) & ~7;
    const rawf4* recs = (const rawf4*)records;
    rawf4 rn = {0.f, 0.f, 0.f, 0.f};
    if (k0 + j < k1) rn = __builtin_nontemporal_load(&recs[(size_t)(k0 + j)]);
    for (int k = k0; k < k1; k += 8) {
        rawf4 r0 = rn;
        rn.x = 0.f; rn.y = 0.f; rn.z = 0.f; rn.w = 0.f;
        int kn = k + 8 + j;
        if (kn < k1) rn = __builtin_nontemporal_load(&recs[(size_t)kn]);
        int s = __float_as_int(r0.x) & 0xFFFFF;
        int mk2 = (int)h2asu(__float2half2_rn(r0.y));
        af01 = __hadd2(af01, uash2(__float_as_uint(r0.z)));
        af23 = __hadd2(af23, uash2(__float_as_uint(r0.w)));
#pragma unroll
        for (int t = 0; t < 8; t++) {
            int st = __shfl(s, base + t);
            unsigned m2 = (unsigned)__shfl(mk2, base + t);
            uint2 q = *((const uint2*)(z16 + 32 * (size_t)st) + j);
            acc01 = __hfma2(uash2(q.x), uash2(m2), acc01);
            acc23 = __hfma2(uash2(q.y), uash2(m2), acc23);
        }
    }
#pragma unroll
    for (int off = 1; off < 8; off <<= 1) {
        af01 = __hadd2(af01, uash2((unsigned)__shfl_xor((int)h2asu(af01), off)));
        af23 = __hadd2(af23, uash2((unsigned)__shfl_xor((int)h2asu(af23), off)));
    }
    float4 hv = {0.f, 0.f, 0.f, 0.f};
    if (active) {
        float2 a01 = __half22float2(acc01);
        float2 a23 = __half22float2(acc23);
        float2 f01 = __half22float2(af01);
        float2 f23 = __half22float2(af23);
        float4 acc = {a01.x, a01.y, a23.x, a23.y};
        const float* wc = &sWe[4 * j];
        float4 w0 = *(const float4*)(wc);
        float4 w1 = *(const float4*)(wc + HH);
        float4 w2 = *(const float4*)(wc + 2 * HH);
        float4 w3 = *(const float4*)(wc + 3 * HH);
        acc.x += f01.x * w0.x + f01.y * w1.x + f23.x * w2.x + f23.y * w3.x;
        acc.y += f01.x * w0.y + f01.y * w1.y + f23.x * w2.y + f23.y * w3.y;
        acc.z += f01.x * w0.z + f01.y * w1.z + f23.x * w2.z + f23.y * w3.z;
        acc.w += f01.x * w0.w + f01.y * w1.w + f23.x * w2.w + f23.y * w3.w;
        hv.x = fmaxf(acc.x, 0.f);
        hv.y = fmaxf(acc.y, 0.f);
        hv.z = fmaxf(acc.z, 0.f);
        hv.w = fmaxf(acc.w, 0.f);
        *(float4*)(h + 4 * (size_t)tid) = hv;
    }
#pragma unroll
    for (int off = 8; off < 64; off <<= 1) {
        hv.x += __shfl_xor(hv.x, off);
        hv.y += __shfl_xor(hv.y, off);
        hv.z += __shfl_xor(hv.z, off);
        hv.w += __shfl_xor(hv.w, off);
    }
    if ((threadIdx.x & 63) < 8) {
        atomicAdd(&sp[4 * j + 0], hv.x);
        atomicAdd(&sp[4 * j + 1], hv.y);
        atomicAdd(&sp[4 * j + 2], hv.z);
        atomicAdd(&sp[4 * j + 3], hv.w);
    }
    __syncthreads();
    if (threadIdx.x < HH) unsafeAtomicAdd(&pooled[threadIdx.x], sp[threadIdx.x]);
}

// fused: g update + node update + next-layer z16
__global__ void update_kernel(const float* __restrict__ h,
                              const float* __restrict__ g_in,
                              float* __restrict__ g_out,
                              const float* __restrict__ pooled,
                              float invN,
                              const float* __restrict__ Wg,
                              const float* __restrict__ bg,
                              const float* __restrict__ Wn,
                              const float* __restrict__ bn,
                              const float* __restrict__ Wout,
                              const float* __restrict__ bout,
                              float* __restrict__ V,
                              const float* __restrict__ Wm,
                              const float* __restrict__ bm,
                              unsigned short* __restrict__ z16,
                              int has_next,
                              int N8)
{
    __shared__ float sWn[64 * HH];
    __shared__ float sWm[34 * HH];
    __shared__ float sgnew[HH];
    __shared__ float sgp[64];
    __shared__ float sWo[HH * 2];
    __shared__ float sb[2 * HH + 2];
    for (int i = threadIdx.x; i < 64 * HH; i += blockDim.x) sWn[i] = Wn[i];
    if (has_next)
        for (int i = threadIdx.x; i < 34 * HH; i += blockDim.x) sWm[i] = Wm[i];
    if (threadIdx.x < 64)
        sgp[threadIdx.x] = (threadIdx.x < HH) ? g_in[threadIdx.x]
                                              : pooled[threadIdx.x - HH] * invN;
    if (threadIdx.x < HH * 2) sWo[threadIdx.x] = Wout[threadIdx.x];
    if (threadIdx.x < HH) sb[threadIdx.x] = bn[threadIdx.x];
    if (threadIdx.x < 2) sb[2 * HH + threadIdx.x] = bout[threadIdx.x];
    if (has_next && threadIdx.x >= 64 && threadIdx.x < 64 + HH)
        sb[HH + threadIdx.x - 64] = bm[threadIdx.x - 64];
    __syncthreads();
    if (threadIdx.x < HH) {
        int k = threadIdx.x;
        float acc = bg[k];
#pragma unroll 8
        for (int i = 0; i < 64; i++) acc += sgp[i] * Wg[i * HH + k];
        sgnew[k] = fmaxf(acc, 0.f);
    }
    __syncthreads();
    if (blockIdx.x == 0 && threadIdx.x < HH) g_out[threadIdx.x] = sgnew[threadIdx.x];

    int tid = blockIdx.x * blockDim.x + threadIdx.x;
    if (tid >= N8) return;
    int v = tid >> 3, j = tid & 7;
    float4 hv = *(const float4*)(h + 4 * (size_t)tid);
    float4 acc;
    acc.x = sb[4 * j + 0]; acc.y = sb[4 * j + 1];
    acc.z = sb[4 * j + 2]; acc.w = sb[4 * j + 3];
#pragma unroll 8
    for (int i = 0; i < HH; i++) {
        float gi = sgnew[i];
        const float4 w = *(const float4*)&sWn[(HH + i) * HH + 4 * j];
        acc.x += gi * w.x; acc.y += gi * w.y;
        acc.z += gi * w.z; acc.w += gi * w.w;
    }
    int base = (threadIdx.x & 63) & ~7;
#pragma unroll
    for (int t = 0; t < 8; t++) {
        float hx = __shfl(hv.x, base + t);
        float hy = __shfl(hv.y, base + t);
        float hz = __shfl(hv.z, base + t);
        float hw = __shfl(hv.w, base + t);
        const float* wr = &sWn[(4 * t) * HH + 4 * j];
        float4 q0 = *(const float4*)(wr);
        float4 q1 = *(const float4*)(wr + HH);
        float4 q2 = *(const float4*)(wr + 2 * HH);
        float4 q3 = *(const float4*)(wr + 3 * HH);
        acc.x += hx * q0.x + hy * q1.x + hz * q2.x + hw * q3.x;
        acc.y += hx * q0.y + hy * q1.y + hz * q2.y + hw * q3.y;
        acc.z += hx * q0.z + hy * q1.z + hz * q2.z + hw * q3.z;
        acc.w += hx * q0.w + hy * q1.w + hz * q2.w + hw * q3.w;
    }
    float4 hn;
    hn.x = fmaxf(acc.x, 0.f);
    hn.y = fmaxf(acc.y, 0.f);
    hn.z = fmaxf(acc.z, 0.f);
    hn.w = fmaxf(acc.w, 0.f);
    float p0 = hn.x * sWo[(4 * j + 0) * 2 + 0] + hn.y * sWo[(4 * j + 1) * 2 + 0]
             + hn.z * sWo[(4 * j + 2) * 2 + 0] + hn.w * sWo[(4 * j + 3) * 2 + 0];
    float p1 = hn.x * sWo[(4 * j + 0) * 2 + 1] + hn.y * sWo[(4 * j + 1) * 2 + 1]
             + hn.z * sWo[(4 * j + 2) * 2 + 1] + hn.w * sWo[(4 * j + 3) * 2 + 1];
#pragma unroll
    for (int off = 1; off < 8; off <<= 1) {
        p0 += __shfl_xor(p0, off);
        p1 += __shfl_xor(p1, off);
    }
    float2 Vold = *(const float2*)(V + 2 * v);
    float2 Vnew;
    Vnew.x = Vold.x + p0 + sb[2 * HH + 0];
    Vnew.y = Vold.y + p1 + sb[2 * HH + 1];
    if (j == 0) *(float2*)(V + 2 * v) = Vnew;
    if (!has_next) return;
    float4 az;
    az.x = sb[HH + 4 * j + 0] + Vnew.x * sWm[4 * j + 0] + Vnew.y * sWm[HH + 4 * j + 0];
    az.y = sb[HH + 4 * j + 1] + Vnew.x * sWm[4 * j + 1] + Vnew.y * sWm[HH + 4 * j + 1];
    az.z = sb[HH + 4 * j + 2] + Vnew.x * sWm[4 * j + 2] + Vnew.y * sWm[HH + 4 * j + 2];
    az.w = sb[HH + 4 * j + 3] + Vnew.x * sWm[4 * j + 3] + Vnew.y * sWm[HH + 4 * j + 3];
#pragma unroll
    for (int t = 0; t < 8; t++) {
        float hx = __shfl(hn.x, base + t);
        float hy = __shfl(hn.y, base + t);
        float hz = __shfl(hn.z, base + t);
        float hw = __shfl(hn.w, base + t);
        const float* wr = &sWm[(2 + 4 * t) * HH + 4 * j];
        float4 q0 = *(const float4*)(wr);
        float4 q1 = *(const float4*)(wr + HH);
        float4 q2 = *(const float4*)(wr + 2 * HH);
        float4 q3 = *(const float4*)(wr + 3 * HH);
        az.x += hx * q0.x + hy * q1.x + hz * q2.x + hw * q3.x;
        az.y += hx * q0.y + hy * q1.y + hz * q2.y + hw * q3.y;
        az.z += hx * q0.z + hy * q1.z + hz * q2.z + hw * q3.z;
        az.w += hx * q0.w + hy * q1.w + hz * q2.w + hw * q3.w;
    }
    uint2 q;
    q.x = pack2h(az.x, az.y);
    q.y = pack2h(az.z, az.w);
    *((uint2*)(z16 + 32 * (size_t)v) + j) = q;
}

extern "C" void kernel_launch(void* const* d_in, const int* in_sizes, int n_in,
                              void* d_out, int out_size, void* d_ws, size_t ws_size,
                              hipStream_t stream)
{
    const float* P     = (const float*)d_in[0];
    const int*   snd   = (const int*)d_in[1];
    const int*   rcv   = (const int*)d_in[2];
    const float* ef    = (const float*)d_in[3];
    const float* mask  = (const float*)d_in[4];
    const float* W_in  = (const float*)d_in[5];
    const float* b_in  = (const float*)d_in[6];
    const float* W_msg = (const float*)d_in[7];
    const float* b_msg = (const float*)d_in[8];
    const float* W_g   = (const float*)d_in[9];
    const float* b_g   = (const float*)d_in[10];
    const float* W_n   = (const float*)d_in[11];
    const float* b_n   = (const float*)d_in[12];
    const float* W_out = (const float*)d_in[13];
    const float* b_out = (const float*)d_in[14];
    float* V = (float*)d_out;

    const int N = in_sizes[0] / 2;
    const int E = in_sizes[1];
    const int N8 = N * 8;
    const int NB = (N + 255) / 256;
    const int nbuck = (N + (1 << BSH) - 1) >> BSH;   // <= 1024 for N<=131072

    dim3 blk(256);
    int gn = (N8 + 255) / 256;
    int ge = (E + 255) / 256;
    int g1 = (E + P1_EPB - 1) / P1_EPB;

    // path-2 eligibility: partition capacity fits the compile-time LDS cap
    long long bexp = ((long long)E << BSH) / (N > 0 ? N : 1);
    int need = (int)((double)bexp + 10.0 * sqrt((double)bexp) + 64.0);
    size_t p2bytes = (size_t)nbuck * P2CAP * 16          // bA + bB
                   + 128ull * (size_t)N                  // h
                   + 64ull * (size_t)N                   // z16
                   + 8ull * (size_t)N                    // F16
                   + 4ull * (MAXB + 7 * HH) + 4096;
    bool p2ok = (need <= P2CAP) && (nbuck <= MAXB) && (N < (1 << 20)) &&
                (ws_size >= p2bytes);

    if (p2ok) {
        uint2* bA = (uint2*)d_ws;
        uint2* bB = bA + (size_t)nbuck * P2CAP;
        float* h = (float*)(bB + (size_t)nbuck * P2CAP);
        unsigned short* z16 = (unsigned short*)(h + (size_t)N * HH);
        uint2* F16 = (uint2*)(z16 + (size_t)N * HH);
        int* tail = (int*)(F16 + N);
        float* pooled = (float*)(tail + MAXB);
        float* g_buf = pooled + 3 * HH;
        (void)hipMemsetAsync(tail, 0, (MAXB + 7 * HH) * sizeof(int), stream);
        pass1_bin_kernel<<<g1, dim3(P1_TPB), 0, stream>>>(snd, rcv, mask, ef, tail,
                                                          bA, bB, E, nbuck, P2CAP);
        init_z_kernel<<<gn, blk, 0, stream>>>(P, W_in, b_in, W_msg, b_msg, h, z16, V, N8);
        for (int l = 0; l < 3; l++) {
            const float* Wm = W_msg + (size_t)l * 38 * HH;
            const float* Wm_next = W_msg + (size_t)(l + 1) * 38 * HH;
            if (l == 0)
                gather_part_kernel<1><<<nbuck, dim3(1024), 0, stream>>>(
                    z16, tail, bA, bB, Wm + 34 * HH, h, F16, pooled + l * HH, N);
            else
                gather_part_kernel<0><<<nbuck, dim3(1024), 0, stream>>>(
                    z16, tail, bA, bB, Wm + 34 * HH, h, F16, pooled + l * HH, N);
            update_kernel<<<gn, blk, 0, stream>>>(h, g_buf + l * HH, g_buf + (l + 1) * HH,
                                                  pooled + l * HH, 1.0f / (float)N,
                                                  W_g + (size_t)l * 64 * HH, b_g + l * HH,
                                                  W_n + (size_t)l * 64 * HH, b_n + l * HH,
                                                  W_out + (size_t)l * HH * 2, b_out + l * 2,
                                                  V,
                                                  (l < 2) ? Wm_next : Wm,
                                                  (l < 2) ? (b_msg + (l + 1) * HH) : (b_msg + l * HH),
                                                  z16, (l < 2) ? 1 : 0, N8);
        }
        return;
    }

    // ---------------- fallback paths (padded / exact CSR) ----------------
    size_t fixed = 128 * (size_t)N + 64 * (size_t)N + 4 * (size_t)N
                 + 4 * (MAXB + 7 * HH) + 4096;
    size_t avail = (ws_size > fixed) ? ws_size - fixed : 0;
    int path, cap = 0;
    {
        long cap1 = (long)(avail / (16 * (size_t)N));
        if (cap1 >= 72) { path = 1; cap = (cap1 > 96) ? 96 : (int)cap1; }
        else             path = 0;
    }

    if (path == 1) {
        float4* records = (float4*)d_ws;
        float*  h       = (float*)(records + (size_t)cap * N);
        unsigned short* z16 = (unsigned short*)(h + (size_t)N * HH);
        int* cnt        = (int*)(z16 + (size_t)N * HH);
        float* pooled   = (float*)(cnt + N);
        float* g_buf    = pooled + 3 * HH;
        (void)hipMemsetAsync(cnt, 0, ((size_t)N + 7 * HH) * sizeof(int), stream);
        build1_kernel<<<ge, blk, 0, stream>>>(snd, rcv, mask, ef, cnt, cap, records, E);
        init_z_kernel<<<gn, blk, 0, stream>>>(P, W_in, b_in, W_msg, b_msg, h, z16, V, N8);
        for (int l = 0; l < 3; l++) {
            const float* Wm = W_msg + (size_t)l * 38 * HH;
            const float* Wm_next = W_msg + (size_t)(l + 1) * 38 * HH;
            gather_kernel<<<gn, blk, 0, stream>>>(z16, cnt, cnt, cap, records,
                                                  Wm + 34 * HH, h, pooled + l * HH, N);
            update_kernel<<<gn, blk, 0, stream>>>(h, g_buf + l * HH, g_buf + (l + 1) * HH,
                                                  pooled + l * HH, 1.0f / (float)N,
                                                  W_g + (size_t)l * 64 * HH, b_g + l * HH,
                                                  W_n + (size_t)l * 64 * HH, b_n + l * HH,
                                                  W_out + (size_t)l * HH * 2, b_out + l * 2,
                                                  V,
                                                  (l < 2) ? Wm_next : Wm,
                                                  (l < 2) ? (b_msg + (l + 1) * HH) : (b_msg + l * HH),
                                                  z16, (l < 2) ? 1 : 0, N8);
        }
    } else {
        float4* records  = (float4*)d_ws;
        float*  h        = (float*)(records + (size_t)E);
        unsigned short* z16 = (unsigned short*)(h + (size_t)N * HH);
        int* cnt         = (int*)(z16 + (size_t)N * HH);
        int* row_start   = cnt + N;
        int* off         = row_start + (N + 1);
        int* bsum        = off + N;
        int* boff        = bsum + 512;
        float* pooled    = (float*)(boff + 512);
        float* g_buf     = pooled + 3 * HH;
        (void)hipMemsetAsync(cnt, 0, ((size_t)(3 * N + 1 + 1024) + 7 * HH) * sizeof(int), stream);
        hist_kernel<<<ge, blk, 0, stream>>>(rcv, cnt, E);
        block_sum_kernel<<<NB, blk, 0, stream>>>(cnt, bsum, N);
        scan_bsum_kernel<<<1, 512, 0, stream>>>(bsum, boff, NB);
        local_scan_kernel<<<NB, blk, 0, stream>>>(cnt, boff, row_start, off, N);
        build0_kernel<<<ge, blk, 0, stream>>>(snd, rcv, mask, ef, off, records, E);
        init_z_kernel<<<gn, blk, 0, stream>>>(P, W_in, b_in, W_msg, b_msg, h, z16, V, N8);
        for (int l = 0; l < 3; l++) {
            const float* Wm = W_msg + (size_t)l * 38 * HH;
            const float* Wm_next = W_msg + (size_t)(l + 1) * 38 * HH;
            gather_kernel<<<gn, blk, 0, stream>>>(z16, row_start, cnt, 0, records,
                                                  Wm + 34 * HH, h, pooled + l * HH, N);
            update_kernel<<<gn, blk, 0, stream>>>(h, g_buf + l * HH, g_buf + (l + 1) * HH,
                                                  pooled + l * HH, 1.0f / (float)N,
                                                  W_g + (size_t)l * 64 * HH, b_g + l * HH,
                                                  W_n + (size_t)l * 64 * HH, b_n + l * HH,
                                                  W_out + (size_t)l * HH * 2, b_out + l * 2,
                                                  V,
                                                  (l < 2) ? Wm_next : Wm,
                                                  (l < 2) ? (b_msg + (l + 1) * HH) : (b_msg + l * HH),
                                                  z16, (l < 2) ? 1 : 0, N8);
        }
    }
}

// Round 11
// 414.724 us; speedup vs baseline: 1.2902x; 1.0238x over previous
//
#include <hip/hip_runtime.h>
#include <hip/hip_fp16.h>
#include <math.h>

// GNN power-flow forward. N=100k, E=3.2M, H=32, L=3, FE=4.
// R21: L0 persists the grouped order; L1/2 skip re-grouping.
//  R20 result (424.6us): gathers now ~50us each, pass1 ~53. L1/2 gathers
//  still read bA twice (62MB) + 1.75M LDS bank conflicts + ~22 barriers to
//  re-derive the grouping L0 already computed. Fix:
//  - gather_part<1> (L0) streams grouped {aS 4B, aM 2B} to FRESH gs/gm
//    arrays (no aliasing) + packed rl[r] = start | len<<13.
//  - gather_seq (L1/2): linear gs/gm -> LDS copy (coalesced, no atomics,
//    1 barrier), bounds from rl, identical phase-B z16 gather + F16.
//  Workspace appends gs/gm/rl after g_buf; existing layout untouched.

#define HH 32        // hidden dim
#define BSH 7        // bucket shift: 128 receivers per partition
#define MAXB 1024    // max partitions (N <= 131072)
#define P2CAP 4992   // fixed per-partition record capacity (path 2)
#define P1_TPB 1024  // pass1 threads per block
#define P1_EPT 8     // pass1 edges per thread
#define P1_EPB (P1_TPB * P1_EPT)   // 8192 edges per block

typedef float rawf4 __attribute__((ext_vector_type(4)));

__device__ __forceinline__ unsigned pack2h(float a, float b) {
    return ((unsigned)__half_as_ushort(__float2half_rn(b)) << 16) |
           (unsigned)__half_as_ushort(__float2half_rn(a));
}
__device__ __forceinline__ __half2 uash2(unsigned u) {
    return *reinterpret_cast<__half2*>(&u);
}
__device__ __forceinline__ unsigned h2asu(__half2 h) {
    return *reinterpret_cast<unsigned*>(&h);
}

// ---------------- build (path 2) ----------------

// pass 1: block-local LDS binning. 8192 edges/block -> LDS hist over
// partitions -> LDS scan -> one global reservation per partition ->
// scatter records into LDS -> coalesced SoA copy-out (A + B arrays).
__global__ void __launch_bounds__(P1_TPB)
pass1_bin_kernel(const int* __restrict__ snd, const int* __restrict__ rcv,
                 const float* __restrict__ mask, const float* __restrict__ ef,
                 int* __restrict__ tail,
                 uint2* __restrict__ bA, uint2* __restrict__ bB,
                 int E, int nbuck, int bcap)
{
    __shared__ float4 srec[P1_EPB];            // 128KB
    __shared__ unsigned short sbid[P1_EPB];    // 16KB
    __shared__ int cur[MAXB];
    __shared__ int dlt[MAXB];
    int lo = blockIdx.x * P1_EPB;
    int n = E - lo; if (n > P1_EPB) n = P1_EPB;
    int t = threadIdx.x;

    for (int i = t; i < MAXB; i += P1_TPB) cur[i] = 0;
    __syncthreads();

    int rv[P1_EPT];
#pragma unroll
    for (int i = 0; i < P1_EPT; i++) {
        int e = lo + t + i * P1_TPB;
        int r = (e < E) ? rcv[e] : -1;
        rv[i] = r;
        if (r >= 0) atomicAdd(&cur[r >> BSH], 1);
    }
    __syncthreads();

    int v = (t < nbuck) ? cur[t] : 0;
    dlt[t] = v;
    __syncthreads();
    for (int off = 1; off < P1_TPB; off <<= 1) {
        int x = (t >= off) ? dlt[t - off] : 0;
        __syncthreads();
        dlt[t] += x;
        __syncthreads();
    }
    int lstart = dlt[t] - v;
    int gbase = 0;
    if (t < nbuck && v > 0) gbase = atomicAdd(&tail[t], v);
    __syncthreads();
    cur[t] = lstart;
    dlt[t] = gbase - lstart;
    __syncthreads();

#pragma unroll
    for (int i = 0; i < P1_EPT; i++) {
        int r = rv[i];
        if (r < 0) continue;
        int e = lo + t + i * P1_TPB;
        int b = r >> BSH;
        int pos = atomicAdd(&cur[b], 1);
        int s = snd[e];
        float mk = mask[e];
        float4 f = *(const float4*)(ef + 4 * (size_t)e);
        float4 rec;
        rec.x = __int_as_float(s | ((r & ((1 << BSH) - 1)) << 20));
        rec.y = mk;
        rec.z = __uint_as_float(pack2h(mk * f.x, mk * f.y));
        rec.w = __uint_as_float(pack2h(mk * f.z, mk * f.w));
        srec[pos] = rec;
        sbid[pos] = (unsigned short)b;
    }
    __syncthreads();

    for (int i = t; i < n; i += P1_TPB) {
        int b = sbid[i];
        unsigned oin = (unsigned)(i + dlt[b]);
        if (oin < (unsigned)bcap) {
            float4 rec = srec[i];
            size_t o = (size_t)b * bcap + oin;
            uint2 a; a.x = __float_as_uint(rec.x); a.y = __float_as_uint(rec.y);
            bA[o] = a;
            uint2 bb; bb.x = __float_as_uint(rec.z); bb.y = __float_as_uint(rec.w);
            bB[o] = bb;
        }
    }
}

// L0 fused group+gather: one block per 128-receiver partition.
// Phase A: LDS hist (lo-word) -> scan -> scatter compact {aS, aM} + bG.
// Write-back: grouped aS/aM streamed to gs/gm (fresh arrays) + rl packed
// start|len per receiver, so L1/2 can skip re-grouping.
// Phase B: 128 groups x 8 lanes z16-gather; af accumulated from bG -> F16.
__global__ void __launch_bounds__(1024)
gather_part_kernel(const unsigned short* __restrict__ z16,
                   const int* __restrict__ tail,
                   const uint2* __restrict__ bA,
                   const uint2* __restrict__ bB,
                   const float* __restrict__ We,   // [4,32] layer 0
                   float* __restrict__ h,
                   uint2* __restrict__ F16,
                   unsigned* __restrict__ gs,
                   unsigned short* __restrict__ gm,
                   unsigned* __restrict__ rl,
                   float* __restrict__ pooled,
                   int N)
{
    __shared__ unsigned aS[P2CAP];          // sender (20b)
    __shared__ unsigned short aM[P2CAP];    // f16 mask
    __shared__ uint2 bG[P2CAP];
    __shared__ int hist[1 << BSH];
    __shared__ int bse[1 << BSH];
    __shared__ int cur[1 << BSH];
    __shared__ float sWe[4 * HH];
    __shared__ float sp[HH];
    int t = threadIdx.x, b = blockIdx.x;
    if (t < (1 << BSH)) hist[t] = 0;
    if (t < 4 * HH) sWe[t] = We[t];
    if (t < HH) sp[t] = 0.0f;
    __syncthreads();
    int n = tail[b];
    if (n > P2CAP) n = P2CAP;
    if (n < 0) n = 0;
    size_t gb = (size_t)b * P2CAP;

    // A1: histogram by rloc (read lo word only; segment stays L2-hot)
    const unsigned* loA = (const unsigned*)(bA + gb);
    for (int i = t; i < n; i += 1024)
        atomicAdd(&hist[(loA[2 * i] >> 20) & ((1 << BSH) - 1)], 1);
    __syncthreads();

    // A2: exclusive scan over 128 rlocs
    if (t < (1 << BSH)) bse[t] = hist[t];
    __syncthreads();
    for (int off = 1; off < (1 << BSH); off <<= 1) {
        int x = (t < (1 << BSH) && t >= off) ? bse[t - off] : 0;
        __syncthreads();
        if (t < (1 << BSH)) bse[t] += x;
        __syncthreads();
    }
    if (t < (1 << BSH)) { int s0 = bse[t] - hist[t]; bse[t] = s0; cur[t] = s0; }
    __syncthreads();

    // A3: scatter into grouped compact LDS lists (re-read is L2-hot)
    for (int i = t; i < n; i += 1024) {
        uint2 a = bA[gb + i];
        int rl2 = (a.x >> 20) & ((1 << BSH) - 1);
        int p = atomicAdd(&cur[rl2], 1);
        aS[p] = a.x & 0xFFFFF;
        aM[p] = __half_as_ushort(__float2half_rn(__uint_as_float(a.y)));
        bG[p] = bB[gb + i];
    }
    __syncthreads();

    // write-back grouped order for L1/2 (fresh arrays, no aliasing)
    for (int i = t; i < n; i += 1024) { gs[gb + i] = aS[i]; gm[gb + i] = aM[i]; }
    if (t < (1 << BSH)) {
        int rr = (b << BSH) + t;
        if (rr < N)
            rl[rr] = (unsigned)bse[t] | ((unsigned)(cur[t] - bse[t]) << 13);
    }

    // Phase B: per-receiver gather. group g handles receiver (b<<7)+g.
    int g = t >> 3, j = t & 7;
    int r = (b << BSH) + g;
    bool active = r < N;
    int k0 = bse[g], k1 = cur[g];
    const __half2 zero2 = __floats2half2_rn(0.f, 0.f);
    __half2 acc01 = zero2, acc23 = zero2, af01 = zero2, af23 = zero2;
    int lanebase = (t & 63) & ~7;
    for (int k = k0; k < k1; k += 8) {
        int idx = k + j;
        int s = 0, mk2 = 0;
        if (idx < k1) {
            s = (int)aS[idx];
            unsigned mv = (unsigned)aM[idx];
            mk2 = (int)(mv | (mv << 16));
            uint2 bb = bG[idx];
            af01 = __hadd2(af01, uash2(bb.x));
            af23 = __hadd2(af23, uash2(bb.y));
        }
#pragma unroll
        for (int q8 = 0; q8 < 8; q8++) {
            int st = __shfl(s, lanebase + q8);
            unsigned m2 = (unsigned)__shfl(mk2, lanebase + q8);
            uint2 qv = *((const uint2*)(z16 + 32 * (size_t)st) + j);
            acc01 = __hfma2(uash2(qv.x), uash2(m2), acc01);
            acc23 = __hfma2(uash2(qv.y), uash2(m2), acc23);
        }
    }
#pragma unroll
    for (int off = 1; off < 8; off <<= 1) {
        af01 = __hadd2(af01, uash2((unsigned)__shfl_xor((int)h2asu(af01), off)));
        af23 = __hadd2(af23, uash2((unsigned)__shfl_xor((int)h2asu(af23), off)));
    }
    if (active && j == 0) {
        uint2 f; f.x = h2asu(af01); f.y = h2asu(af23);
        F16[r] = f;
    }
    float4 hv = {0.f, 0.f, 0.f, 0.f};
    if (active) {
        float2 a01 = __half22float2(acc01);
        float2 a23 = __half22float2(acc23);
        float2 f01 = __half22float2(af01);
        float2 f23 = __half22float2(af23);
        float4 acc = {a01.x, a01.y, a23.x, a23.y};
        const float* wc = &sWe[4 * j];
        float4 w0 = *(const float4*)(wc);
        float4 w1 = *(const float4*)(wc + HH);
        float4 w2 = *(const float4*)(wc + 2 * HH);
        float4 w3 = *(const float4*)(wc + 3 * HH);
        acc.x += f01.x * w0.x + f01.y * w1.x + f23.x * w2.x + f23.y * w3.x;
        acc.y += f01.x * w0.y + f01.y * w1.y + f23.x * w2.y + f23.y * w3.y;
        acc.z += f01.x * w0.z + f01.y * w1.z + f23.x * w2.z + f23.y * w3.z;
        acc.w += f01.x * w0.w + f01.y * w1.w + f23.x * w2.w + f23.y * w3.w;
        hv.x = fmaxf(acc.x, 0.f);
        hv.y = fmaxf(acc.y, 0.f);
        hv.z = fmaxf(acc.z, 0.f);
        hv.w = fmaxf(acc.w, 0.f);
        rawf4 hvr;
        hvr.x = hv.x; hvr.y = hv.y; hvr.z = hv.z; hvr.w = hv.w;
        __builtin_nontemporal_store(hvr, (rawf4*)(h + 32 * (size_t)r + 4 * j));
    }
#pragma unroll
    for (int off = 8; off < 64; off <<= 1) {
        hv.x += __shfl_xor(hv.x, off);
        hv.y += __shfl_xor(hv.y, off);
        hv.z += __shfl_xor(hv.z, off);
        hv.w += __shfl_xor(hv.w, off);
    }
    if ((t & 63) < 8) {
        atomicAdd(&sp[4 * j + 0], hv.x);
        atomicAdd(&sp[4 * j + 1], hv.y);
        atomicAdd(&sp[4 * j + 2], hv.z);
        atomicAdd(&sp[4 * j + 3], hv.w);
    }
    __syncthreads();
    if (t < HH) unsafeAtomicAdd(&pooled[t], sp[t]);
}

// L1/2 gather: grouped data already in gs/gm (written by L0). Linear copy
// into LDS (coalesced, no atomics), bounds from rl, then identical phase B
// with the cached F16 epilogue.
__global__ void __launch_bounds__(1024)
gather_seq_kernel(const unsigned short* __restrict__ z16,
                  const int* __restrict__ tail,
                  const unsigned* __restrict__ gs,
                  const unsigned short* __restrict__ gm,
                  const unsigned* __restrict__ rl,
                  const uint2* __restrict__ F16,
                  const float* __restrict__ We,   // [4,32]
                  float* __restrict__ h,
                  float* __restrict__ pooled,
                  int N)
{
    __shared__ unsigned aS[P2CAP];
    __shared__ unsigned short aM[P2CAP];
    __shared__ float sWe[4 * HH];
    __shared__ float sp[HH];
    int t = threadIdx.x, b = blockIdx.x;
    if (t < 4 * HH) sWe[t] = We[t];
    if (t < HH) sp[t] = 0.0f;
    int n = tail[b];
    if (n > P2CAP) n = P2CAP;
    if (n < 0) n = 0;
    size_t gb = (size_t)b * P2CAP;
    for (int i = t; i < n; i += 1024) { aS[i] = gs[gb + i]; aM[i] = gm[gb + i]; }
    __syncthreads();

    int g = t >> 3, j = t & 7;
    int r = (b << BSH) + g;
    bool active = r < N;
    int k0 = 0, k1 = 0;
    if (active) {
        unsigned w = rl[r];
        k0 = (int)(w & 8191u);
        k1 = k0 + (int)((w >> 13) & 8191u);
    }
    const __half2 zero2 = __floats2half2_rn(0.f, 0.f);
    __half2 acc01 = zero2, acc23 = zero2, af01 = zero2, af23 = zero2;
    int lanebase = (t & 63) & ~7;
    for (int k = k0; k < k1; k += 8) {
        int idx = k + j;
        int s = 0, mk2 = 0;
        if (idx < k1) {
            s = (int)aS[idx];
            unsigned mv = (unsigned)aM[idx];
            mk2 = (int)(mv | (mv << 16));
        }
#pragma unroll
        for (int q8 = 0; q8 < 8; q8++) {
            int st = __shfl(s, lanebase + q8);
            unsigned m2 = (unsigned)__shfl(mk2, lanebase + q8);
            uint2 qv = *((const uint2*)(z16 + 32 * (size_t)st) + j);
            acc01 = __hfma2(uash2(qv.x), uash2(m2), acc01);
            acc23 = __hfma2(uash2(qv.y), uash2(m2), acc23);
        }
    }
    if (active) {
        uint2 f = F16[r];
        af01 = uash2(f.x);
        af23 = uash2(f.y);
    }
    float4 hv = {0.f, 0.f, 0.f, 0.f};
    if (active) {
        float2 a01 = __half22float2(acc01);
        float2 a23 = __half22float2(acc23);
        float2 f01 = __half22float2(af01);
        float2 f23 = __half22float2(af23);
        float4 acc = {a01.x, a01.y, a23.x, a23.y};
        const float* wc = &sWe[4 * j];
        float4 w0 = *(const float4*)(wc);
        float4 w1 = *(const float4*)(wc + HH);
        float4 w2 = *(const float4*)(wc + 2 * HH);
        float4 w3 = *(const float4*)(wc + 3 * HH);
        acc.x += f01.x * w0.x + f01.y * w1.x + f23.x * w2.x + f23.y * w3.x;
        acc.y += f01.x * w0.y + f01.y * w1.y + f23.x * w2.y + f23.y * w3.y;
        acc.z += f01.x * w0.z + f01.y * w1.z + f23.x * w2.z + f23.y * w3.z;
        acc.w += f01.x * w0.w + f01.y * w1.w + f23.x * w2.w + f23.y * w3.w;
        hv.x = fmaxf(acc.x, 0.f);
        hv.y = fmaxf(acc.y, 0.f);
        hv.z = fmaxf(acc.z, 0.f);
        hv.w = fmaxf(acc.w, 0.f);
        rawf4 hvr;
        hvr.x = hv.x; hvr.y = hv.y; hvr.z = hv.z; hvr.w = hv.w;
        __builtin_nontemporal_store(hvr, (rawf4*)(h + 32 * (size_t)r + 4 * j));
    }
#pragma unroll
    for (int off = 8; off < 64; off <<= 1) {
        hv.x += __shfl_xor(hv.x, off);
        hv.y += __shfl_xor(hv.y, off);
        hv.z += __shfl_xor(hv.z, off);
        hv.w += __shfl_xor(hv.w, off);
    }
    if ((t & 63) < 8) {
        atomicAdd(&sp[4 * j + 0], hv.x);
        atomicAdd(&sp[4 * j + 1], hv.y);
        atomicAdd(&sp[4 * j + 2], hv.z);
        atomicAdd(&sp[4 * j + 3], hv.w);
    }
    __syncthreads();
    if (t < HH) unsafeAtomicAdd(&pooled[t], sp[t]);
}

// ---------------- single-pass padded build (path 1 fallback) ----------------

__global__ void build1_kernel(const int* __restrict__ snd, const int* __restrict__ rcv,
                              const float* __restrict__ mask, const float* __restrict__ ef,
                              int* __restrict__ slot, int cap,
                              float4* __restrict__ records, int E)
{
    int e = blockIdx.x * blockDim.x + threadIdx.x;
    if (e >= E) return;
    int r = rcv[e];
    int t = atomicAdd(&slot[r], 1);
    if (t >= cap) return;
    size_t pos = (size_t)cap * r + t;
    int s = snd[e];
    float mk = mask[e];
    float4 f = *(const float4*)(ef + 4 * (size_t)e);
    float4 rec;
    rec.x = __int_as_float(s);
    rec.y = mk;
    rec.z = __uint_as_float(pack2h(mk * f.x, mk * f.y));
    rec.w = __uint_as_float(pack2h(mk * f.z, mk * f.w));
    records[pos] = rec;
}

// ---------------- exact-CSR fallback (path 0) ----------------

__global__ void hist_kernel(const int* __restrict__ rcv, int* __restrict__ deg, int E)
{
    int e = blockIdx.x * blockDim.x + threadIdx.x;
    if (e < E) atomicAdd(&deg[rcv[e]], 1);
}

__global__ void block_sum_kernel(const int* __restrict__ deg, int* __restrict__ bsum, int N)
{
    __shared__ int s[256];
    int i = blockIdx.x * 256 + threadIdx.x;
    s[threadIdx.x] = (i < N) ? deg[i] : 0;
    __syncthreads();
    for (int off = 128; off > 0; off >>= 1) {
        if (threadIdx.x < off) s[threadIdx.x] += s[threadIdx.x + off];
        __syncthreads();
    }
    if (threadIdx.x == 0) bsum[blockIdx.x] = s[0];
}

__global__ void scan_bsum_kernel(const int* __restrict__ bsum, int* __restrict__ boff, int NB)
{
    __shared__ int s[512];
    int t = threadIdx.x;
    int v = (t < NB) ? bsum[t] : 0;
    s[t] = v;
    __syncthreads();
    for (int off = 1; off < 512; off <<= 1) {
        int x = (t >= off) ? s[t - off] : 0;
        __syncthreads();
        s[t] += x;
        __syncthreads();
    }
    if (t < NB) boff[t] = s[t] - v;
}

__global__ void local_scan_kernel(const int* __restrict__ deg, const int* __restrict__ boff,
                                  int* __restrict__ row_start, int* __restrict__ off, int N)
{
    __shared__ int s[256];
    int i = blockIdx.x * 256 + threadIdx.x;
    int v = (i < N) ? deg[i] : 0;
    s[threadIdx.x] = v;
    __syncthreads();
    for (int o = 1; o < 256; o <<= 1) {
        int x = (threadIdx.x >= o) ? s[threadIdx.x - o] : 0;
        __syncthreads();
        s[threadIdx.x] += x;
        __syncthreads();
    }
    if (i < N) {
        int r = boff[blockIdx.x] + s[threadIdx.x] - v;
        row_start[i] = r;
        off[i] = r;
    }
}

__global__ void build0_kernel(const int* __restrict__ snd, const int* __restrict__ rcv,
                              const float* __restrict__ mask, const float* __restrict__ ef,
                              int* __restrict__ slot,
                              float4* __restrict__ records, int E)
{
    int e = blockIdx.x * blockDim.x + threadIdx.x;
    if (e >= E) return;
    int r = rcv[e];
    int t = atomicAdd(&slot[r], 1);
    int s = snd[e];
    float mk = mask[e];
    float4 f = *(const float4*)(ef + 4 * (size_t)e);
    float4 rec;
    rec.x = __int_as_float(s);
    rec.y = mk;
    rec.z = __uint_as_float(pack2h(mk * f.x, mk * f.y));
    rec.w = __uint_as_float(pack2h(mk * f.z, mk * f.w));
    records[(size_t)t] = rec;
}

// ---------------- node-side kernels ----------------

__global__ void init_z_kernel(const float* __restrict__ P,
                              const float* __restrict__ W_in,
                              const float* __restrict__ b_in,
                              const float* __restrict__ Wm,   // [38,32] layer 0
                              const float* __restrict__ bm,
                              float* __restrict__ h,
                              unsigned short* __restrict__ z16,
                              float* __restrict__ V,
                              int N8)
{
    __shared__ float sW[34 * HH];
    __shared__ float sWin[2 * HH];
    __shared__ float sbin[HH];
    __shared__ float sbm[HH];
    for (int i = threadIdx.x; i < 34 * HH; i += blockDim.x) sW[i] = Wm[i];
    if (threadIdx.x < 2 * HH) sWin[threadIdx.x] = W_in[threadIdx.x];
    if (threadIdx.x < HH) { sbin[threadIdx.x] = b_in[threadIdx.x]; sbm[threadIdx.x] = bm[threadIdx.x]; }
    __syncthreads();
    int tid = blockIdx.x * blockDim.x + threadIdx.x;
    if (tid >= N8) return;
    int v = tid >> 3, j = tid & 7;
    float2 p = *(const float2*)(P + 2 * (size_t)v);
    float4 w0 = *(const float4*)&sWin[4 * j];
    float4 w1 = *(const float4*)&sWin[HH + 4 * j];
    float4 b  = *(const float4*)&sbin[4 * j];
    float4 hv;
    hv.x = b.x + p.x * w0.x + p.y * w1.x;
    hv.y = b.y + p.x * w0.y + p.y * w1.y;
    hv.z = b.z + p.x * w0.z + p.y * w1.z;
    hv.w = b.w + p.x * w0.w + p.y * w1.w;
    *(float4*)(h + 4 * (size_t)tid) = hv;
    if (j == 0) { V[2 * v] = 1.0f; V[2 * v + 1] = 0.0f; }
    float4 acc;
    acc.x = sbm[4 * j + 0] + sW[4 * j + 0];
    acc.y = sbm[4 * j + 1] + sW[4 * j + 1];
    acc.z = sbm[4 * j + 2] + sW[4 * j + 2];
    acc.w = sbm[4 * j + 3] + sW[4 * j + 3];
    int base = (threadIdx.x & 63) & ~7;
#pragma unroll
    for (int t = 0; t < 8; t++) {
        float hx = __shfl(hv.x, base + t);
        float hy = __shfl(hv.y, base + t);
        float hz = __shfl(hv.z, base + t);
        float hw = __shfl(hv.w, base + t);
        const float* wr = &sW[(2 + 4 * t) * HH + 4 * j];
        float4 q0 = *(const float4*)(wr);
        float4 q1 = *(const float4*)(wr + HH);
        float4 q2 = *(const float4*)(wr + 2 * HH);
        float4 q3 = *(const float4*)(wr + 3 * HH);
        acc.x += hx * q0.x + hy * q1.x + hz * q2.x + hw * q3.x;
        acc.y += hx * q0.y + hy * q1.y + hz * q2.y + hw * q3.y;
        acc.z += hx * q0.z + hy * q1.z + hz * q2.z + hw * q3.z;
        acc.w += hx * q0.w + hy * q1.w + hz * q2.w + hw * q3.w;
    }
    uint2 q;
    q.x = pack2h(acc.x, acc.y);
    q.y = pack2h(acc.z, acc.w);
    *((uint2*)(z16 + 32 * (size_t)v) + j) = q;
}

// classic pull-gather (fallback paths 0/1; reads padded/CSR records)
__global__ void __launch_bounds__(256)
gather_kernel(const unsigned short* __restrict__ z16,
              const int* __restrict__ row_start,
              const int* __restrict__ cnt,
              int cap,
              const float4* __restrict__ records,
              const float* __restrict__ We,   // [4,32]
              float* __restrict__ h,
              float* __restrict__ pooled,
              int N)
{
    __shared__ float sWe[4 * HH];
    __shared__ float sp[HH];
    if (threadIdx.x < 4 * HH) sWe[threadIdx.x] = We[threadIdx.x];
    if (threadIdx.x < HH) sp[threadIdx.x] = 0.0f;
    __syncthreads();
    int tid = blockIdx.x * blockDim.x + threadIdx.x;
    int v = tid >> 3, j = tid & 7;
    bool active = v < N;
    int k0 = 0, k1 = 0;
    if (active) {
        int len = cnt[v];
        if (cap > 0) {
            if (len > cap) len = cap;
            k0 = cap * v;
        } else {
            k0 = row_start[v];
        }
        k1 = k0 + len;
    }
    const __half2 zero2 = __floats2half2_rn(0.f, 0.f);
    __half2 acc01 = zero2, acc23 = zero2;
    __half2 af01 = zero2, af23 = zero2;
    int base = (threadIdx.x & 63) & ~7;
    const rawf4* recs = (const rawf4*)records;
    rawf4 rn = {0.f, 0.f, 0.f, 0.f};
    if (k0 + j < k1) rn = __builtin_nontemporal_load(&recs[(size_t)(k0 + j)]);
    for (int k = k0; k < k1; k += 8) {
        rawf4 r0 = rn;
        rn.x = 0.f; rn.y = 0.f; rn.z = 0.f; rn.w = 0.f;
        int kn = k + 8 + j;
        if (kn < k1) rn = __builtin_nontemporal_load(&recs[(size_t)kn]);
        int s = __float_as_int(r0.x) & 0xFFFFF;
        int mk2 = (int)h2asu(__float2half2_rn(r0.y));
        af01 = __hadd2(af01, uash2(__float_as_uint(r0.z)));
        af23 = __hadd2(af23, uash2(__float_as_uint(r0.w)));
#pragma unroll
        for (int t = 0; t < 8; t++) {
            int st = __shfl(s, base + t);
            unsigned m2 = (unsigned)__shfl(mk2, base + t);
            uint2 q = *((const uint2*)(z16 + 32 * (size_t)st) + j);
            acc01 = __hfma2(uash2(q.x), uash2(m2), acc01);
            acc23 = __hfma2(uash2(q.y), uash2(m2), acc23);
        }
    }
#pragma unroll
    for (int off = 1; off < 8; off <<= 1) {
        af01 = __hadd2(af01, uash2((unsigned)__shfl_xor((int)h2asu(af01), off)));
        af23 = __hadd2(af23, uash2((unsigned)__shfl_xor((int)h2asu(af23), off)));
    }
    float4 hv = {0.f, 0.f, 0.f, 0.f};
    if (active) {
        float2 a01 = __half22float2(acc01);
        float2 a23 = __half22float2(acc23);
        float2 f01 = __half22float2(af01);
        float2 f23 = __half22float2(af23);
        float4 acc = {a01.x, a01.y, a23.x, a23.y};
        const float* wc = &sWe[4 * j];
        float4 w0 = *(const float4*)(wc);
        float4 w1 = *(const float4*)(wc + HH);
        float4 w2 = *(const float4*)(wc + 2 * HH);
        float4 w3 = *(const float4*)(wc + 3 * HH);
        acc.x += f01.x * w0.x + f01.y * w1.x + f23.x * w2.x + f23.y * w3.x;
        acc.y += f01.x * w0.y + f01.y * w1.y + f23.x * w2.y + f23.y * w3.y;
        acc.z += f01.x * w0.z + f01.y * w1.z + f23.x * w2.z + f23.y * w3.z;
        acc.w += f01.x * w0.w + f01.y * w1.w + f23.x * w2.w + f23.y * w3.w;
        hv.x = fmaxf(acc.x, 0.f);
        hv.y = fmaxf(acc.y, 0.f);
        hv.z = fmaxf(acc.z, 0.f);
        hv.w = fmaxf(acc.w, 0.f);
        *(float4*)(h + 4 * (size_t)tid) = hv;
    }
#pragma unroll
    for (int off = 8; off < 64; off <<= 1) {
        hv.x += __shfl_xor(hv.x, off);
        hv.y += __shfl_xor(hv.y, off);
        hv.z += __shfl_xor(hv.z, off);
        hv.w += __shfl_xor(hv.w, off);
    }
    if ((threadIdx.x & 63) < 8) {
        atomicAdd(&sp[4 * j + 0], hv.x);
        atomicAdd(&sp[4 * j + 1], hv.y);
        atomicAdd(&sp[4 * j + 2], hv.z);
        atomicAdd(&sp[4 * j + 3], hv.w);
    }
    __syncthreads();
    if (threadIdx.x < HH) unsafeAtomicAdd(&pooled[threadIdx.x], sp[threadIdx.x]);
}

// fused: g update + node update + next-layer z16
__global__ void update_kernel(const float* __restrict__ h,
                              const float* __restrict__ g_in,
                              float* __restrict__ g_out,
                              const float* __restrict__ pooled,
                              float invN,
                              const float* __restrict__ Wg,
                              const float* __restrict__ bg,
                              const float* __restrict__ Wn,
                              const float* __restrict__ bn,
                              const float* __restrict__ Wout,
                              const float* __restrict__ bout,
                              float* __restrict__ V,
                              const float* __restrict__ Wm,
                              const float* __restrict__ bm,
                              unsigned short* __restrict__ z16,
                              int has_next,
                              int N8)
{
    __shared__ float sWn[64 * HH];
    __shared__ float sWm[34 * HH];
    __shared__ float sgnew[HH];
    __shared__ float sgp[64];
    __shared__ float sWo[HH * 2];
    __shared__ float sb[2 * HH + 2];
    for (int i = threadIdx.x; i < 64 * HH; i += blockDim.x) sWn[i] = Wn[i];
    if (has_next)
        for (int i = threadIdx.x; i < 34 * HH; i += blockDim.x) sWm[i] = Wm[i];
    if (threadIdx.x < 64)
        sgp[threadIdx.x] = (threadIdx.x < HH) ? g_in[threadIdx.x]
                                              : pooled[threadIdx.x - HH] * invN;
    if (threadIdx.x < HH * 2) sWo[threadIdx.x] = Wout[threadIdx.x];
    if (threadIdx.x < HH) sb[threadIdx.x] = bn[threadIdx.x];
    if (threadIdx.x < 2) sb[2 * HH + threadIdx.x] = bout[threadIdx.x];
    if (has_next && threadIdx.x >= 64 && threadIdx.x < 64 + HH)
        sb[HH + threadIdx.x - 64] = bm[threadIdx.x - 64];
    __syncthreads();
    if (threadIdx.x < HH) {
        int k = threadIdx.x;
        float acc = bg[k];
#pragma unroll 8
        for (int i = 0; i < 64; i++) acc += sgp[i] * Wg[i * HH + k];
        sgnew[k] = fmaxf(acc, 0.f);
    }
    __syncthreads();
    if (blockIdx.x == 0 && threadIdx.x < HH) g_out[threadIdx.x] = sgnew[threadIdx.x];

    int tid = blockIdx.x * blockDim.x + threadIdx.x;
    if (tid >= N8) return;
    int v = tid >> 3, j = tid & 7;
    float4 hv = *(const float4*)(h + 4 * (size_t)tid);
    float4 acc;
    acc.x = sb[4 * j + 0]; acc.y = sb[4 * j + 1];
    acc.z = sb[4 * j + 2]; acc.w = sb[4 * j + 3];
#pragma unroll 8
    for (int i = 0; i < HH; i++) {
        float gi = sgnew[i];
        const float4 w = *(const float4*)&sWn[(HH + i) * HH + 4 * j];
        acc.x += gi * w.x; acc.y += gi * w.y;
        acc.z += gi * w.z; acc.w += gi * w.w;
    }
    int base = (threadIdx.x & 63) & ~7;
#pragma unroll
    for (int t = 0; t < 8; t++) {
        float hx = __shfl(hv.x, base + t);
        float hy = __shfl(hv.y, base + t);
        float hz = __shfl(hv.z, base + t);
        float hw = __shfl(hv.w, base + t);
        const float* wr = &sWn[(4 * t) * HH + 4 * j];
        float4 q0 = *(const float4*)(wr);
        float4 q1 = *(const float4*)(wr + HH);
        float4 q2 = *(const float4*)(wr + 2 * HH);
        float4 q3 = *(const float4*)(wr + 3 * HH);
        acc.x += hx * q0.x + hy * q1.x + hz * q2.x + hw * q3.x;
        acc.y += hx * q0.y + hy * q1.y + hz * q2.y + hw * q3.y;
        acc.z += hx * q0.z + hy * q1.z + hz * q2.z + hw * q3.z;
        acc.w += hx * q0.w + hy * q1.w + hz * q2.w + hw * q3.w;
    }
    float4 hn;
    hn.x = fmaxf(acc.x, 0.f);
    hn.y = fmaxf(acc.y, 0.f);
    hn.z = fmaxf(acc.z, 0.f);
    hn.w = fmaxf(acc.w, 0.f);
    float p0 = hn.x * sWo[(4 * j + 0) * 2 + 0] + hn.y * sWo[(4 * j + 1) * 2 + 0]
             + hn.z * sWo[(4 * j + 2) * 2 + 0] + hn.w * sWo[(4 * j + 3) * 2 + 0];
    float p1 = hn.x * sWo[(4 * j + 0) * 2 + 1] + hn.y * sWo[(4 * j + 1) * 2 + 1]
             + hn.z * sWo[(4 * j + 2) * 2 + 1] + hn.w * sWo[(4 * j + 3) * 2 + 1];
#pragma unroll
    for (int off = 1; off < 8; off <<= 1) {
        p0 += __shfl_xor(p0, off);
        p1 += __shfl_xor(p1, off);
    }
    float2 Vold = *(const float2*)(V + 2 * v);
    float2 Vnew;
    Vnew.x = Vold.x + p0 + sb[2 * HH + 0];
    Vnew.y = Vold.y + p1 + sb[2 * HH + 1];
    if (j == 0) *(float2*)(V + 2 * v) = Vnew;
    if (!has_next) return;
    float4 az;
    az.x = sb[HH + 4 * j + 0] + Vnew.x * sWm[4 * j + 0] + Vnew.y * sWm[HH + 4 * j + 0];
    az.y = sb[HH + 4 * j + 1] + Vnew.x * sWm[4 * j + 1] + Vnew.y * sWm[HH + 4 * j + 1];
    az.z = sb[HH + 4 * j + 2] + Vnew.x * sWm[4 * j + 2] + Vnew.y * sWm[HH + 4 * j + 2];
    az.w = sb[HH + 4 * j + 3] + Vnew.x * sWm[4 * j + 3] + Vnew.y * sWm[HH + 4 * j + 3];
#pragma unroll
    for (int t = 0; t < 8; t++) {
        float hx = __shfl(hn.x, base + t);
        float hy = __shfl(hn.y, base + t);
        float hz = __shfl(hn.z, base + t);
        float hw = __shfl(hn.w, base + t);
        const float* wr = &sWm[(2 + 4 * t) * HH + 4 * j];
        float4 q0 = *(const float4*)(wr);
        float4 q1 = *(const float4*)(wr + HH);
        float4 q2 = *(const float4*)(wr + 2 * HH);
        float4 q3 = *(const float4*)(wr + 3 * HH);
        az.x += hx * q0.x + hy * q1.x + hz * q2.x + hw * q3.x;
        az.y += hx * q0.y + hy * q1.y + hz * q2.y + hw * q3.y;
        az.z += hx * q0.z + hy * q1.z + hz * q2.z + hw * q3.z;
        az.w += hx * q0.w + hy * q1.w + hz * q2.w + hw * q3.w;
    }
    uint2 q;
    q.x = pack2h(az.x, az.y);
    q.y = pack2h(az.z, az.w);
    *((uint2*)(z16 + 32 * (size_t)v) + j) = q;
}

extern "C" void kernel_launch(void* const* d_in, const int* in_sizes, int n_in,
                              void* d_out, int out_size, void* d_ws, size_t ws_size,
                              hipStream_t stream)
{
    const float* P     = (const float*)d_in[0];
    const int*   snd   = (const int*)d_in[1];
    const int*   rcv   = (const int*)d_in[2];
    const float* ef    = (const float*)d_in[3];
    const float* mask  = (const float*)d_in[4];
    const float* W_in  = (const float*)d_in[5];
    const float* b_in  = (const float*)d_in[6];
    const float* W_msg = (const float*)d_in[7];
    const float* b_msg = (const float*)d_in[8];
    const float* W_g   = (const float*)d_in[9];
    const float* b_g   = (const float*)d_in[10];
    const float* W_n   = (const float*)d_in[11];
    const float* b_n   = (const float*)d_in[12];
    const float* W_out = (const float*)d_in[13];
    const float* b_out = (const float*)d_in[14];
    float* V = (float*)d_out;

    const int N = in_sizes[0] / 2;
    const int E = in_sizes[1];
    const int N8 = N * 8;
    const int NB = (N + 255) / 256;
    const int nbuck = (N + (1 << BSH) - 1) >> BSH;   // <= 1024 for N<=131072

    dim3 blk(256);
    int gn = (N8 + 255) / 256;
    int ge = (E + 255) / 256;
    int g1 = (E + P1_EPB - 1) / P1_EPB;

    // path-2 eligibility: partition capacity fits the compile-time LDS cap
    long long bexp = ((long long)E << BSH) / (N > 0 ? N : 1);
    int need = (int)((double)bexp + 10.0 * sqrt((double)bexp) + 64.0);
    size_t K = (size_t)nbuck * P2CAP;
    size_t p2bytes = 16ull * K                           // bA + bB
                   + 6ull * K + 64                       // gs + gm
                   + 128ull * (size_t)N                  // h
                   + 64ull * (size_t)N                   // z16
                   + 8ull * (size_t)N                    // F16
                   + 4ull * (size_t)N                    // rl
                   + 4ull * (MAXB + 7 * HH) + 4096;
    bool p2ok = (need <= P2CAP) && (nbuck <= MAXB) && (N < (1 << 20)) &&
                (ws_size >= p2bytes);

    if (p2ok) {
        uint2* bA = (uint2*)d_ws;
        uint2* bB = bA + K;
        float* h = (float*)(bB + K);
        unsigned short* z16 = (unsigned short*)(h + (size_t)N * HH);
        uint2* F16 = (uint2*)(z16 + (size_t)N * HH);
        int* tail = (int*)(F16 + N);
        float* pooled = (float*)(tail + MAXB);
        float* g_buf = pooled + 3 * HH;
        unsigned* gs = (unsigned*)(g_buf + 4 * HH);            // 4B * K
        size_t K2 = (K + 1) & ~(size_t)1;
        unsigned short* gm = (unsigned short*)(gs + K);        // 2B * K
        unsigned* rl = (unsigned*)(gm + K2);                   // 4B * N
        (void)hipMemsetAsync(tail, 0, (MAXB + 7 * HH) * sizeof(int), stream);
        pass1_bin_kernel<<<g1, dim3(P1_TPB), 0, stream>>>(snd, rcv, mask, ef, tail,
                                                          bA, bB, E, nbuck, P2CAP);
        init_z_kernel<<<gn, blk, 0, stream>>>(P, W_in, b_in, W_msg, b_msg, h, z16, V, N8);
        for (int l = 0; l < 3; l++) {
            const float* Wm = W_msg + (size_t)l * 38 * HH;
            const float* Wm_next = W_msg + (size_t)(l + 1) * 38 * HH;
            if (l == 0)
                gather_part_kernel<<<nbuck, dim3(1024), 0, stream>>>(
                    z16, tail, bA, bB, Wm + 34 * HH, h, F16, gs, gm, rl,
                    pooled + l * HH, N);
            else
                gather_seq_kernel<<<nbuck, dim3(1024), 0, stream>>>(
                    z16, tail, gs, gm, rl, F16, Wm + 34 * HH, h,
                    pooled + l * HH, N);
            update_kernel<<<gn, blk, 0, stream>>>(h, g_buf + l * HH, g_buf + (l + 1) * HH,
                                                  pooled + l * HH, 1.0f / (float)N,
                                                  W_g + (size_t)l * 64 * HH, b_g + l * HH,
                                                  W_n + (size_t)l * 64 * HH, b_n + l * HH,
                                                  W_out + (size_t)l * HH * 2, b_out + l * 2,
                                                  V,
                                                  (l < 2) ? Wm_next : Wm,
                                                  (l < 2) ? (b_msg + (l + 1) * HH) : (b_msg + l * HH),
                                                  z16, (l < 2) ? 1 : 0, N8);
        }
        return;
    }

    // ---------------- fallback paths (padded / exact CSR) ----------------
    size_t fixed = 128 * (size_t)N + 64 * (size_t)N + 4 * (size_t)N
                 + 4 * (MAXB + 7 * HH) + 4096;
    size_t avail = (ws_size > fixed) ? ws_size - fixed : 0;
    int path, cap = 0;
    {
        long cap1 = (long)(avail / (16 * (size_t)N));
        if (cap1 >= 72) { path = 1; cap = (cap1 > 96) ? 96 : (int)cap1; }
        else             path = 0;
    }

    if (path == 1) {
        float4* records = (float4*)d_ws;
        float*  h       = (float*)(records + (size_t)cap * N);
        unsigned short* z16 = (unsigned short*)(h + (size_t)N * HH);
        int* cnt        = (int*)(z16 + (size_t)N * HH);
        float* pooled   = (float*)(cnt + N);
        float* g_buf    = pooled + 3 * HH;
        (void)hipMemsetAsync(cnt, 0, ((size_t)N + 7 * HH) * sizeof(int), stream);
        build1_kernel<<<ge, blk, 0, stream>>>(snd, rcv, mask, ef, cnt, cap, records, E);
        init_z_kernel<<<gn, blk, 0, stream>>>(P, W_in, b_in, W_msg, b_msg, h, z16, V, N8);
        for (int l = 0; l < 3; l++) {
            const float* Wm = W_msg + (size_t)l * 38 * HH;
            const float* Wm_next = W_msg + (size_t)(l + 1) * 38 * HH;
            gather_kernel<<<gn, blk, 0, stream>>>(z16, cnt, cnt, cap, records,
                                                  Wm + 34 * HH, h, pooled + l * HH, N);
            update_kernel<<<gn, blk, 0, stream>>>(h, g_buf + l * HH, g_buf + (l + 1) * HH,
                                                  pooled + l * HH, 1.0f / (float)N,
                                                  W_g + (size_t)l * 64 * HH, b_g + l * HH,
                                                  W_n + (size_t)l * 64 * HH, b_n + l * HH,
                                                  W_out + (size_t)l * HH * 2, b_out + l * 2,
                                                  V,
                                                  (l < 2) ? Wm_next : Wm,
                                                  (l < 2) ? (b_msg + (l + 1) * HH) : (b_msg + l * HH),
                                                  z16, (l < 2) ? 1 : 0, N8);
        }
    } else {
        float4* records  = (float4*)d_ws;
        float*  h        = (float*)(records + (size_t)E);
        unsigned short* z16 = (unsigned short*)(h + (size_t)N * HH);
        int* cnt         = (int*)(z16 + (size_t)N * HH);
        int* row_start   = cnt + N;
        int* off         = row_start + (N + 1);
        int* bsum        = off + N;
        int* boff        = bsum + 512;
        float* pooled    = (float*)(boff + 512);
        float* g_buf     = pooled + 3 * HH;
        (void)hipMemsetAsync(cnt, 0, ((size_t)(3 * N + 1 + 1024) + 7 * HH) * sizeof(int), stream);
        hist_kernel<<<ge, blk, 0, stream>>>(rcv, cnt, E);
        block_sum_kernel<<<NB, blk, 0, stream>>>(cnt, bsum, N);
        scan_bsum_kernel<<<1, 512, 0, stream>>>(bsum, boff, NB);
        local_scan_kernel<<<NB, blk, 0, stream>>>(cnt, boff, row_start, off, N);
        build0_kernel<<<ge, blk, 0, stream>>>(snd, rcv, mask, ef, off, records, E);
        init_z_kernel<<<gn, blk, 0, stream>>>(P, W_in, b_in, W_msg, b_msg, h, z16, V, N8);
        for (int l = 0; l < 3; l++) {
            const float* Wm = W_msg + (size_t)l * 38 * HH;
            const float* Wm_next = W_msg + (size_t)(l + 1) * 38 * HH;
            gather_kernel<<<gn, blk, 0, stream>>>(z16, row_start, cnt, 0, records,
                                                  Wm + 34 * HH, h, pooled + l * HH, N);
            update_kernel<<<gn, blk, 0, stream>>>(h, g_buf + l * HH, g_buf + (l + 1) * HH,
                                                  pooled + l * HH, 1.0f / (float)N,
                                                  W_g + (size_t)l * 64 * HH, b_g + l * HH,
                                                  W_n + (size_t)l * 64 * HH, b_n + l * HH,
                                                  W_out + (size_t)l * HH * 2, b_out + l * 2,
                                                  V,
                                                  (l < 2) ? Wm_next : Wm,
                                                  (l < 2) ? (b_msg + (l + 1) * HH) : (b_msg + l * HH),
                                                  z16, (l < 2) ? 1 : 0, N8);
        }
    }
}